// Round 1
// 538.516 us; speedup vs baseline: 1.0800x; 1.0800x over previous
//
#include <hip/hip_runtime.h>

#define B_ 8
#define T_ 2048
#define D_ 1024

typedef __attribute__((ext_vector_type(8))) short bf16x8;
typedef __attribute__((ext_vector_type(8))) _Float16 f16x8;
typedef __attribute__((ext_vector_type(4))) float f32x4;
typedef __attribute__((ext_vector_type(8))) unsigned short u16x8;
typedef __attribute__((ext_vector_type(4))) unsigned short u16x4;

__device__ __forceinline__ unsigned short f2bf(float f) {
  union { float f; unsigned u; } v; v.f = f;
  unsigned r = v.u + 0x7FFFu + ((v.u >> 16) & 1u);  // RNE (finite inputs only)
  return (unsigned short)(r >> 16);
}
__device__ __forceinline__ float bf2f(unsigned short h) {
  union { unsigned u; float f; } v; v.u = ((unsigned)h) << 16; return v.f;
}
__device__ __forceinline__ unsigned short f2h(float f) {
  union { _Float16 h; unsigned short u; } v; v.h = (_Float16)f; return v.u;
}

// async global->LDS, 16B/lane; LDS dest = wave-uniform base + lane*16
__device__ __forceinline__ void gl2lds16(const void* g, void* l) {
  __builtin_amdgcn_global_load_lds(
      (__attribute__((address_space(1))) void*)g,
      (__attribute__((address_space(3))) void*)l, 16, 0, 0);
}

// ---------------------------------------------------------------------------
// Prep: x fp32 -> x_hi/x_lo bf16 (row-major, for scores) + xT fp16 [b,d,t]
// (single plane, for av's B operand).
// ---------------------------------------------------------------------------
__global__ __launch_bounds__(256) void prep_kernel(
    const float* __restrict__ x,
    unsigned short* __restrict__ xh, unsigned short* __restrict__ xl,
    unsigned short* __restrict__ xth) {
  const int b = blockIdx.z;
  const int t0 = blockIdx.y << 6;
  const int d0 = blockIdx.x << 6;
  __shared__ unsigned short tf[64][68];  // fp16 bits, transpose staging
  const int tid = threadIdx.x;
  const int row = tid & 63, cq = tid >> 6;
  const size_t xoff = ((size_t)b * T_ + t0 + row) * D_ + d0;
#pragma unroll
  for (int c = 0; c < 4; ++c) {
    const int col = (cq << 4) + (c << 2);
    const float4 v = *(const float4*)(x + xoff + col);
    const unsigned short h0 = f2bf(v.x), h1 = f2bf(v.y), h2 = f2bf(v.z), h3 = f2bf(v.w);
    const unsigned short l0 = f2bf(v.x - bf2f(h0)), l1 = f2bf(v.y - bf2f(h1));
    const unsigned short l2 = f2bf(v.z - bf2f(h2)), l3 = f2bf(v.w - bf2f(h3));
    u16x4 hv = {h0, h1, h2, h3}, lv = {l0, l1, l2, l3};
    *(u16x4*)(xh + xoff + col) = hv;
    *(u16x4*)(xl + xoff + col) = lv;
    tf[col + 0][row] = f2h(v.x); tf[col + 1][row] = f2h(v.y);
    tf[col + 2][row] = f2h(v.z); tf[col + 3][row] = f2h(v.w);
  }
  __syncthreads();
  const size_t toff = ((size_t)b * D_ + d0 + row) * T_ + t0;
#pragma unroll
  for (int c = 0; c < 4; ++c) {
    const int col = (cq << 4) + (c << 2);
    *(u16x4*)(xth + toff + col) = *(const u16x4*)&tf[row][col];
  }
}

// ---------------------------------------------------------------------------
// Scores: S = x.x^T, causal tiles, 3-product split-bf16 MFMA (err ~2^-17).
// 128x128 tile, BK=32, global_load_lds staging, XOR-swizzled LDS chunk slots.
// This round: flat 1088-block causal grid (no dead blocks) with bijective XCD
// swizzle (XCD k == batch k); __launch_bounds__(256,4) to get 4 waves/SIMD
// (occupancy was the limiter: ~150 unified VGPR+AGPR -> 3 waves/SIMD); B
// fragments streamed inside the j-loop (-24 live VGPRs) and the 3 products
// emitted as independent runs of 4 MFMAs (no 3-deep dependent C chains).
// ---------------------------------------------------------------------------
__global__ __launch_bounds__(256, 4) void scores_mfma(
    const unsigned short* __restrict__ xh, const unsigned short* __restrict__ xl,
    float* __restrict__ w) {
  // flat causal grid: 8 batches x 136 lower-tri tiles. id%8 = XCD, and
  // (id%8)*136+(id/8) gives XCD k exactly batch k (1088 = 8*136).
  const int id = blockIdx.x;
  const int sid = ((id & 7) * 136) + (id >> 3);
  const int b = sid / 136;
  const int L = sid - b * 136;
  int tt = (int)((sqrtf(8.f * (float)L + 1.f) - 1.f) * 0.5f);
  while (((tt + 1) * (tt + 2) >> 1) <= L) ++tt;
  while (((tt * (tt + 1)) >> 1) > L) --tt;
  const int ts = L - ((tt * (tt + 1)) >> 1);

  const int t0 = tt << 7, s0 = ts << 7;
  __shared__ unsigned short Ah[128 * 32];
  __shared__ unsigned short Al[128 * 32];
  __shared__ unsigned short Bh[128 * 32];
  __shared__ unsigned short Bl[128 * 32];
  const int tid = threadIdx.x;
  const int lane = tid & 63, wv = tid >> 6;
  const int wr = (wv >> 1) << 6, wc = (wv & 1) << 6;
  const int quad = lane >> 4, r16 = lane & 15;
  const int swz = ((quad ^ (r16 & 3) ^ ((r16 >> 2) & 1)) << 3);  // shorts
  const size_t xb = (size_t)b * T_ * D_;

  f32x4 acc[4][4];
#pragma unroll
  for (int i = 0; i < 4; ++i)
#pragma unroll
    for (int j = 0; j < 4; ++j) acc[i][j] = (f32x4){0.f, 0.f, 0.f, 0.f};

  for (int k0 = 0; k0 < D_; k0 += 32) {
    __syncthreads();
#pragma unroll
    for (int i = 0; i < 2; ++i) {
      const int cc = (wv << 7) + (i << 6) + lane;  // 16B chunk id 0..511
      const int row = cc >> 2, q = cc & 3;
      const int gq = q ^ (row & 3) ^ ((row >> 2) & 1);
      const int ldsoff = (((wv << 7) + (i << 6)) << 3);  // wave-uniform, shorts
      const size_t ga = xb + (size_t)(t0 + row) * D_ + k0 + (gq << 3);
      const size_t gb = xb + (size_t)(s0 + row) * D_ + k0 + (gq << 3);
      gl2lds16(xh + ga, &Ah[ldsoff]);
      gl2lds16(xl + ga, &Al[ldsoff]);
      gl2lds16(xh + gb, &Bh[ldsoff]);
      gl2lds16(xl + gb, &Bl[ldsoff]);
    }
    __syncthreads();
    // A fragments hoisted (32 VGPR live); B fragments streamed per-j (8 live).
    bf16x8 ah[4], al[4];
#pragma unroll
    for (int i = 0; i < 4; ++i) {
      const int ra = ((wr + (i << 4) + r16) << 5) + swz;
      ah[i] = *(const bf16x8*)&Ah[ra];
      al[i] = *(const bf16x8*)&Al[ra];
    }
#pragma unroll
    for (int j = 0; j < 4; ++j) {
      const int rb = ((wc + (j << 4) + r16) << 5) + swz;
      const bf16x8 bhj = *(const bf16x8*)&Bh[rb];
      const bf16x8 blj = *(const bf16x8*)&Bl[rb];
#pragma unroll
      for (int i = 0; i < 4; ++i)
        acc[i][j] = __builtin_amdgcn_mfma_f32_16x16x32_bf16(ah[i], bhj, acc[i][j], 0, 0, 0);
#pragma unroll
      for (int i = 0; i < 4; ++i)
        acc[i][j] = __builtin_amdgcn_mfma_f32_16x16x32_bf16(ah[i], blj, acc[i][j], 0, 0, 0);
#pragma unroll
      for (int i = 0; i < 4; ++i)
        acc[i][j] = __builtin_amdgcn_mfma_f32_16x16x32_bf16(al[i], bhj, acc[i][j], 0, 0, 0);
    }
  }

  float* wb = w + (size_t)b * T_ * T_;
#pragma unroll
  for (int i = 0; i < 4; ++i)
#pragma unroll
    for (int j = 0; j < 4; ++j) {
      const int rr = t0 + wr + (i << 4) + (quad << 2);
      const int cc = s0 + wc + (j << 4) + r16;
#pragma unroll
      for (int rg = 0; rg < 4; ++rg)
        wb[(size_t)(rr + rg) * T_ + cc] = acc[i][j][rg];
    }
}

// ---------------------------------------------------------------------------
// Softmax: one wave per row, 32 vals/lane in registers, masked (causal-only)
// loads. Writes full fp32 rows (zeros above diag; row 0 uniform) and, if EMIT,
// fp16 W up to the 128-tile boundary (what av consumes). fp16 row 0 = zeros
// over s<128 (row 0 of out is produced by the row0 kernels instead).
// ---------------------------------------------------------------------------
template <bool EMIT>
__global__ __launch_bounds__(256) void softmax_kernel(float* __restrict__ w,
                                                      unsigned short* __restrict__ wf) {
  const int row = (blockIdx.x << 2) + (threadIdx.x >> 6);  // b*T + t
  const int t = row & (T_ - 1);
  const int lane = threadIdx.x & 63;
  float* wr = w + (size_t)row * T_;
  unsigned short* wfr = wf + (size_t)row * T_;

  if (t == 0) {
    const float u = 1.0f / 2048.0f;
#pragma unroll
    for (int k = 0; k < 32; ++k) {
      wr[lane + (k << 6)] = u;
      if (EMIT && k < 2) wfr[lane + (k << 6)] = 0;  // av reads row 0 only s<128
    }
    return;
  }

  const int kmax = ((t >> 7) + 1) << 1;  // 64-chunks covering the causal tiles
  float v[32];
  float m = -3.0e38f;
#pragma unroll
  for (int k = 0; k < 32; ++k) {
    const int s = lane + (k << 6);
    float val = -1.0e30f;
    if (s < t) val = wr[s];  // exec-masked load: upper half never fetched
    v[k] = val;
    m = fmaxf(m, val);
  }
#pragma unroll
  for (int off = 32; off; off >>= 1) m = fmaxf(m, __shfl_xor(m, off));

  float l = 0.f;
#pragma unroll
  for (int k = 0; k < 32; ++k) {
    v[k] = __expf(v[k] - m);  // masked slots -> exactly 0.0f
    l += v[k];
  }
#pragma unroll
  for (int off = 32; off; off >>= 1) l += __shfl_xor(l, off);
  const float inv = 1.0f / l;

#pragma unroll
  for (int k = 0; k < 32; ++k) {
    const float o = v[k] * inv;
    const int s = lane + (k << 6);
    wr[s] = o;
    if (EMIT && k < kmax) wfr[s] = f2h(o);
  }
}

// ---------------------------------------------------------------------------
// AV: out = W.x, single-product fp16 MFMA. 128x128 tile, BK=32, swizzled LDS.
// Causal k-range only (row 0 written later by row0 kernels). blockIdx.x
// encodes (td, tt_idx) so the 8 td-blocks sharing a W tile land on one XCD
// (linear%8 heuristic) and each XCD gets tt pair {k, 15-k} = identical total
// k-steps. __launch_bounds__(256,4) keeps 4 waves/SIMD resident.
// ---------------------------------------------------------------------------
template <bool USE_WF16>
__global__ __launch_bounds__(256, 4) void av_mfma(
    const float* __restrict__ w, const unsigned short* __restrict__ wf,
    const unsigned short* __restrict__ xth, float* __restrict__ out) {
  const int xid = blockIdx.x;
  const int td = xid >> 4;
  const int ti = xid & 15;
  const int tt = (ti < 8) ? ti : (23 - ti);  // XCD k gets {k, 15-k}
  const int b = blockIdx.z;
  const int t0 = tt << 7, d0 = td << 7;
  __shared__ unsigned short Aw[128 * 32];
  __shared__ unsigned short Bx[128 * 32];
  const int tid = threadIdx.x;
  const int lane = tid & 63, wv = tid >> 6;
  const int wr = (wv >> 1) << 6, wc = (wv & 1) << 6;
  const int quad = lane >> 4, r16 = lane & 15;
  const int swz = ((quad ^ (r16 & 3) ^ ((r16 >> 2) & 1)) << 3);
  const size_t xtb = (size_t)b * D_ * T_;
  const size_t wbase = (size_t)b * T_ * T_;
  const int smax = t0 + 128;

  f32x4 acc[4][4];
#pragma unroll
  for (int i = 0; i < 4; ++i)
#pragma unroll
    for (int j = 0; j < 4; ++j) acc[i][j] = (f32x4){0.f, 0.f, 0.f, 0.f};

  for (int s0 = 0; s0 < smax; s0 += 32) {
    __syncthreads();
    if (USE_WF16) {
#pragma unroll
      for (int i = 0; i < 2; ++i) {
        const int cc = (wv << 7) + (i << 6) + lane;
        const int row = cc >> 2, q = cc & 3;
        const int gq = q ^ (row & 3) ^ ((row >> 2) & 1);
        const int ldsoff = (((wv << 7) + (i << 6)) << 3);
        gl2lds16(wf + wbase + (size_t)(t0 + row) * T_ + s0 + (gq << 3), &Aw[ldsoff]);
      }
    } else {
      const int row = tid >> 1, half = tid & 1;
      const float* g = w + wbase + (size_t)(t0 + row) * T_ + s0 + (half << 4);
      const float4 v0 = ((const float4*)g)[0];
      const float4 v1 = ((const float4*)g)[1];
      const float4 v2 = ((const float4*)g)[2];
      const float4 v3 = ((const float4*)g)[3];
      const int sw = (row & 3) ^ ((row >> 2) & 1);
      u16x8 p0 = {f2h(v0.x), f2h(v0.y), f2h(v0.z), f2h(v0.w),
                  f2h(v1.x), f2h(v1.y), f2h(v1.z), f2h(v1.w)};
      u16x8 p1 = {f2h(v2.x), f2h(v2.y), f2h(v2.z), f2h(v2.w),
                  f2h(v3.x), f2h(v3.y), f2h(v3.z), f2h(v3.w)};
      *(u16x8*)&Aw[(row << 5) + ((((half << 1) | 0) ^ sw) << 3)] = p0;
      *(u16x8*)&Aw[(row << 5) + ((((half << 1) | 1) ^ sw) << 3)] = p1;
    }
#pragma unroll
    for (int i = 0; i < 2; ++i) {
      const int cc = (wv << 7) + (i << 6) + lane;
      const int row = cc >> 2, q = cc & 3;
      const int gq = q ^ (row & 3) ^ ((row >> 2) & 1);
      const int ldsoff = (((wv << 7) + (i << 6)) << 3);
      gl2lds16(xth + xtb + (size_t)(d0 + row) * T_ + s0 + (gq << 3), &Bx[ldsoff]);
    }
    __syncthreads();
    f16x8 a[4];
#pragma unroll
    for (int i = 0; i < 4; ++i)
      a[i] = *(const f16x8*)&Aw[((wr + (i << 4) + r16) << 5) + swz];
#pragma unroll
    for (int j = 0; j < 4; ++j) {
      const f16x8 bbj = *(const f16x8*)&Bx[((wc + (j << 4) + r16) << 5) + swz];
#pragma unroll
      for (int i = 0; i < 4; ++i)
        acc[i][j] = __builtin_amdgcn_mfma_f32_16x16x32_f16(a[i], bbj, acc[i][j], 0, 0, 0);
    }
  }

  float* ob = out + (size_t)b * T_ * D_;
#pragma unroll
  for (int i = 0; i < 4; ++i)
#pragma unroll
    for (int j = 0; j < 4; ++j) {
      const int rr = t0 + wr + (i << 4) + (quad << 2);
      const int cc = d0 + wc + (j << 4) + r16;
#pragma unroll
      for (int rg = 0; rg < 4; ++rg)
        ob[(size_t)(rr + rg) * D_ + cc] = acc[i][j][rg];
    }
}

// ---------------------------------------------------------------------------
// Row 0 of out = mean over all T rows of x (uniform weights, faithful to ref).
// ---------------------------------------------------------------------------
__global__ __launch_bounds__(256) void row0_partial(const float* __restrict__ x,
                                                    float* __restrict__ part) {
  const int tc = blockIdx.x, b = blockIdx.y;
  const int tid = threadIdx.x;
  const float* xb = x + ((size_t)b * T_ + (tc << 8)) * D_;
  float4 s = {0.f, 0.f, 0.f, 0.f};
#pragma unroll 4
  for (int r = 0; r < 256; ++r) {
    const float4 v = *(const float4*)(xb + (size_t)r * D_ + (tid << 2));
    s.x += v.x; s.y += v.y; s.z += v.z; s.w += v.w;
  }
  *(float4*)(part + ((size_t)((b << 3) + tc)) * D_ + (tid << 2)) = s;
}

__global__ __launch_bounds__(256) void row0_reduce(const float* __restrict__ part,
                                                   float* __restrict__ out) {
  const int b = blockIdx.x;
  const int tid = threadIdx.x;
  float4 s = {0.f, 0.f, 0.f, 0.f};
#pragma unroll
  for (int p = 0; p < 8; ++p) {
    const float4 v = *(const float4*)(part + ((size_t)((b << 3) + p)) * D_ + (tid << 2));
    s.x += v.x; s.y += v.y; s.z += v.z; s.w += v.w;
  }
  const float sc = 1.0f / 2048.0f;
  float4 o = {s.x * sc, s.y * sc, s.z * sc, s.w * sc};
  *(float4*)(out + (size_t)b * T_ * D_ + (tid << 2)) = o;  // row t=0
}

// ---------------------------------------------------------------------------
extern "C" void kernel_launch(void* const* d_in, const int* in_sizes, int n_in,
                              void* d_out, int out_size, void* d_ws, size_t ws_size,
                              hipStream_t stream) {
  const float* x = (const float*)d_in[0];
  float* att_vec = (float*)d_out;                   // [B,T,D] output 0
  float* w = (float*)d_out + (size_t)B_ * T_ * D_;  // [B,T,T] output 1

  // xh/xl (bf16, row-major) staged in the att_vec region; consumed by scores
  // before av/row0 overwrite it.
  unsigned short* xh = (unsigned short*)att_vec;
  unsigned short* xl = xh + (size_t)B_ * T_ * D_;
  // workspace: xT fp16 (33.5 MB) + W fp16 (67 MB) + row0 partials (256 KB)
  const size_t xthN = (size_t)B_ * D_ * T_;
  const size_t wfN = (size_t)B_ * T_ * T_;
  unsigned short* xth = (unsigned short*)d_ws;
  unsigned short* wf16 = xth + xthN;
  const size_t need = xthN * 2 + wfN * 2 + (size_t)64 * D_ * 4;
  const bool use_wf16 = (ws_size >= need);
  float* part = use_wf16 ? (float*)(wf16 + wfN) : (float*)(xth + xthN);

  prep_kernel<<<dim3(D_ / 64, T_ / 64, B_), 256, 0, stream>>>(x, xh, xl, xth);
  scores_mfma<<<dim3(8 * 136), 256, 0, stream>>>(xh, xl, w);
  if (use_wf16) {
    softmax_kernel<true><<<dim3(B_ * T_ / 4), 256, 0, stream>>>(w, wf16);
    av_mfma<true><<<dim3(128, 1, B_), 256, 0, stream>>>(w, wf16, xth, att_vec);
  } else {
    softmax_kernel<false><<<dim3(B_ * T_ / 4), 256, 0, stream>>>(w, wf16);
    av_mfma<false><<<dim3(128, 1, B_), 256, 0, stream>>>(w, wf16, xth, att_vec);
  }
  row0_partial<<<dim3(8, B_), 256, 0, stream>>>(x, part);
  row0_reduce<<<dim3(B_), 256, 0, stream>>>(part, att_vec);
}

// Round 3
// 509.632 us; speedup vs baseline: 1.1412x; 1.0567x over previous
//
#include <hip/hip_runtime.h>

#define B_ 8
#define T_ 2048
#define D_ 1024

typedef __attribute__((ext_vector_type(8))) short bf16x8;
typedef __attribute__((ext_vector_type(8))) _Float16 f16x8;
typedef __attribute__((ext_vector_type(4))) float f32x4;
typedef __attribute__((ext_vector_type(8))) unsigned short u16x8;
typedef __attribute__((ext_vector_type(4))) unsigned short u16x4;

__device__ __forceinline__ unsigned short f2bf(float f) {
  union { float f; unsigned u; } v; v.f = f;
  unsigned r = v.u + 0x7FFFu + ((v.u >> 16) & 1u);  // RNE (finite inputs only)
  return (unsigned short)(r >> 16);
}
__device__ __forceinline__ float bf2f(unsigned short h) {
  union { unsigned u; float f; } v; v.u = ((unsigned)h) << 16; return v.f;
}
__device__ __forceinline__ unsigned short f2h(float f) {
  union { _Float16 h; unsigned short u; } v; v.h = (_Float16)f; return v.u;
}

// async global->LDS, 16B/lane; LDS dest = wave-uniform base + lane*16
__device__ __forceinline__ void gl2lds16(const void* g, void* l) {
  __builtin_amdgcn_global_load_lds(
      (__attribute__((address_space(1))) void*)g,
      (__attribute__((address_space(3))) void*)l, 16, 0, 0);
}

// ---------------------------------------------------------------------------
// Prep: x fp32 -> x_hi/x_lo bf16 (row-major, for scores) + xT fp16 [b,d,t]
// (single plane, for av's B operand).
// ---------------------------------------------------------------------------
__global__ __launch_bounds__(256) void prep_kernel(
    const float* __restrict__ x,
    unsigned short* __restrict__ xh, unsigned short* __restrict__ xl,
    unsigned short* __restrict__ xth) {
  const int b = blockIdx.z;
  const int t0 = blockIdx.y << 6;
  const int d0 = blockIdx.x << 6;
  __shared__ unsigned short tf[64][68];  // fp16 bits, transpose staging
  const int tid = threadIdx.x;
  const int row = tid & 63, cq = tid >> 6;
  const size_t xoff = ((size_t)b * T_ + t0 + row) * D_ + d0;
#pragma unroll
  for (int c = 0; c < 4; ++c) {
    const int col = (cq << 4) + (c << 2);
    const float4 v = *(const float4*)(x + xoff + col);
    const unsigned short h0 = f2bf(v.x), h1 = f2bf(v.y), h2 = f2bf(v.z), h3 = f2bf(v.w);
    const unsigned short l0 = f2bf(v.x - bf2f(h0)), l1 = f2bf(v.y - bf2f(h1));
    const unsigned short l2 = f2bf(v.z - bf2f(h2)), l3 = f2bf(v.w - bf2f(h3));
    u16x4 hv = {h0, h1, h2, h3}, lv = {l0, l1, l2, l3};
    *(u16x4*)(xh + xoff + col) = hv;
    *(u16x4*)(xl + xoff + col) = lv;
    tf[col + 0][row] = f2h(v.x); tf[col + 1][row] = f2h(v.y);
    tf[col + 2][row] = f2h(v.z); tf[col + 3][row] = f2h(v.w);
  }
  __syncthreads();
  const size_t toff = ((size_t)b * D_ + d0 + row) * T_ + t0;
#pragma unroll
  for (int c = 0; c < 4; ++c) {
    const int col = (cq << 4) + (c << 2);
    *(u16x4*)(xth + toff + col) = *(const u16x4*)&tf[row][col];
  }
}

// ---------------------------------------------------------------------------
// Scores: S = x.x^T, causal tiles, 3-product split-bf16 MFMA (err ~2^-17).
// 128x128 tile, BK=32, global_load_lds staging, XOR-swizzled LDS chunk slots.
// Flat 1088-block causal grid, bijective XCD swizzle (XCD k == batch k),
// __launch_bounds__(256,4), streamed B fragments. At the m97-structure
// MfmaUtil ceiling (~37%) — untouched.
// ---------------------------------------------------------------------------
__global__ __launch_bounds__(256, 4) void scores_mfma(
    const unsigned short* __restrict__ xh, const unsigned short* __restrict__ xl,
    float* __restrict__ w) {
  const int id = blockIdx.x;
  const int sid = ((id & 7) * 136) + (id >> 3);
  const int b = sid / 136;
  const int L = sid - b * 136;
  int tt = (int)((sqrtf(8.f * (float)L + 1.f) - 1.f) * 0.5f);
  while (((tt + 1) * (tt + 2) >> 1) <= L) ++tt;
  while (((tt * (tt + 1)) >> 1) > L) --tt;
  const int ts = L - ((tt * (tt + 1)) >> 1);

  const int t0 = tt << 7, s0 = ts << 7;
  __shared__ unsigned short Ah[128 * 32];
  __shared__ unsigned short Al[128 * 32];
  __shared__ unsigned short Bh[128 * 32];
  __shared__ unsigned short Bl[128 * 32];
  const int tid = threadIdx.x;
  const int lane = tid & 63, wv = tid >> 6;
  const int wr = (wv >> 1) << 6, wc = (wv & 1) << 6;
  const int quad = lane >> 4, r16 = lane & 15;
  const int swz = ((quad ^ (r16 & 3) ^ ((r16 >> 2) & 1)) << 3);  // shorts
  const size_t xb = (size_t)b * T_ * D_;

  f32x4 acc[4][4];
#pragma unroll
  for (int i = 0; i < 4; ++i)
#pragma unroll
    for (int j = 0; j < 4; ++j) acc[i][j] = (f32x4){0.f, 0.f, 0.f, 0.f};

  for (int k0 = 0; k0 < D_; k0 += 32) {
    __syncthreads();
#pragma unroll
    for (int i = 0; i < 2; ++i) {
      const int cc = (wv << 7) + (i << 6) + lane;  // 16B chunk id 0..511
      const int row = cc >> 2, q = cc & 3;
      const int gq = q ^ (row & 3) ^ ((row >> 2) & 1);
      const int ldsoff = (((wv << 7) + (i << 6)) << 3);  // wave-uniform, shorts
      const size_t ga = xb + (size_t)(t0 + row) * D_ + k0 + (gq << 3);
      const size_t gb = xb + (size_t)(s0 + row) * D_ + k0 + (gq << 3);
      gl2lds16(xh + ga, &Ah[ldsoff]);
      gl2lds16(xl + ga, &Al[ldsoff]);
      gl2lds16(xh + gb, &Bh[ldsoff]);
      gl2lds16(xl + gb, &Bl[ldsoff]);
    }
    __syncthreads();
    bf16x8 ah[4], al[4];
#pragma unroll
    for (int i = 0; i < 4; ++i) {
      const int ra = ((wr + (i << 4) + r16) << 5) + swz;
      ah[i] = *(const bf16x8*)&Ah[ra];
      al[i] = *(const bf16x8*)&Al[ra];
    }
#pragma unroll
    for (int j = 0; j < 4; ++j) {
      const int rb = ((wc + (j << 4) + r16) << 5) + swz;
      const bf16x8 bhj = *(const bf16x8*)&Bh[rb];
      const bf16x8 blj = *(const bf16x8*)&Bl[rb];
#pragma unroll
      for (int i = 0; i < 4; ++i)
        acc[i][j] = __builtin_amdgcn_mfma_f32_16x16x32_bf16(ah[i], bhj, acc[i][j], 0, 0, 0);
#pragma unroll
      for (int i = 0; i < 4; ++i)
        acc[i][j] = __builtin_amdgcn_mfma_f32_16x16x32_bf16(ah[i], blj, acc[i][j], 0, 0, 0);
#pragma unroll
      for (int i = 0; i < 4; ++i)
        acc[i][j] = __builtin_amdgcn_mfma_f32_16x16x32_bf16(al[i], bhj, acc[i][j], 0, 0, 0);
    }
  }

  float* wb = w + (size_t)b * T_ * T_;
#pragma unroll
  for (int i = 0; i < 4; ++i)
#pragma unroll
    for (int j = 0; j < 4; ++j) {
      const int rr = t0 + wr + (i << 4) + (quad << 2);
      const int cc = s0 + wc + (j << 4) + r16;
#pragma unroll
      for (int rg = 0; rg < 4; ++rg)
        wb[(size_t)(rr + rg) * T_ + cc] = acc[i][j][rg];
    }
}

// ---------------------------------------------------------------------------
// Softmax: one wave per row, float4-vectorized (8 x 1KB/wave loads + stores,
// was 32 scalar — G13). Masked chunk loads skip the upper half; per-element
// select keeps garbage out of the max. Writes full fp32 rows and, if EMIT,
// fp16 W up to the 128-tile boundary.
// ---------------------------------------------------------------------------
template <bool EMIT>
__global__ __launch_bounds__(256) void softmax_kernel(float* __restrict__ w,
                                                      unsigned short* __restrict__ wf) {
  const int row = (blockIdx.x << 2) + (threadIdx.x >> 6);  // b*T + t
  const int t = row & (T_ - 1);
  const int lane = threadIdx.x & 63;
  float* wr = w + (size_t)row * T_;
  unsigned short* wfr = wf + (size_t)row * T_;

  if (t == 0) {
    const float u = 1.0f / 2048.0f;
    const float4 uv = {u, u, u, u};
#pragma unroll
    for (int k = 0; k < 8; ++k) *(float4*)&wr[(lane << 2) + (k << 8)] = uv;
    if (EMIT && lane < 32) {  // av reads row 0 only s<128
      u16x4 z = {0, 0, 0, 0};
      *(u16x4*)&wfr[lane << 2] = z;
    }
    return;
  }

  float4 v[8];
  float m = -3.0e38f;
#pragma unroll
  for (int k = 0; k < 8; ++k) {
    const int s = (lane << 2) + (k << 8);
    float4 val = {-1.0e30f, -1.0e30f, -1.0e30f, -1.0e30f};
    if (s < t) {  // exec-masked: fully-upper chunks never fetched
      const float4 g = *(const float4*)&wr[s];
      val.x = g.x;
      val.y = (s + 1 < t) ? g.y : -1.0e30f;
      val.z = (s + 2 < t) ? g.z : -1.0e30f;
      val.w = (s + 3 < t) ? g.w : -1.0e30f;
    }
    v[k] = val;
    m = fmaxf(m, fmaxf(fmaxf(val.x, val.y), fmaxf(val.z, val.w)));
  }
#pragma unroll
  for (int off = 32; off; off >>= 1) m = fmaxf(m, __shfl_xor(m, off));

  float l = 0.f;
#pragma unroll
  for (int k = 0; k < 8; ++k) {
    v[k].x = __expf(v[k].x - m);  // masked slots -> exactly 0.0f
    v[k].y = __expf(v[k].y - m);
    v[k].z = __expf(v[k].z - m);
    v[k].w = __expf(v[k].w - m);
    l += (v[k].x + v[k].y) + (v[k].z + v[k].w);
  }
#pragma unroll
  for (int off = 32; off; off >>= 1) l += __shfl_xor(l, off);
  const float inv = 1.0f / l;

  const int smax_emit = ((t >> 7) + 1) << 7;  // 128-tile boundary
#pragma unroll
  for (int k = 0; k < 8; ++k) {
    const int s = (lane << 2) + (k << 8);
    const float4 o = {v[k].x * inv, v[k].y * inv, v[k].z * inv, v[k].w * inv};
    *(float4*)&wr[s] = o;
    if (EMIT && s < smax_emit) {
      u16x4 h = {f2h(o.x), f2h(o.y), f2h(o.z), f2h(o.w)};
      *(u16x4*)&wfr[s] = h;
    }
  }
}

// ---------------------------------------------------------------------------
// AV: out = W.x, single-product fp16 MFMA. 128x128 tile, BK=64 (32KB LDS
// total -> still 5 blocks/CU; halves barrier drains; 32 MFMAs/stage phase).
// 8-slot XOR swizzle (slot = chunk ^ (row&7)) keeps ds_read_b128 at <=2-way.
// ---------------------------------------------------------------------------
template <bool USE_WF16>
__global__ __launch_bounds__(256, 4) void av_mfma(
    const float* __restrict__ w, const unsigned short* __restrict__ wf,
    const unsigned short* __restrict__ xth, float* __restrict__ out) {
  const int xid = blockIdx.x;
  const int td = xid >> 4;
  const int ti = xid & 15;
  const int tt = (ti < 8) ? ti : (23 - ti);  // XCD k gets {k, 15-k}
  const int b = blockIdx.z;
  const int t0 = tt << 7, d0 = td << 7;
  __shared__ unsigned short Aw[128 * 64];
  __shared__ unsigned short Bx[128 * 64];
  const int tid = threadIdx.x;
  const int lane = tid & 63, wv = tid >> 6;
  const int wr = (wv >> 1) << 6, wc = (wv & 1) << 6;
  const int quad = lane >> 4, r16 = lane & 15;
  const size_t xtb = (size_t)b * D_ * T_;
  const size_t wbase = (size_t)b * T_ * T_;
  const int smax = t0 + 128;

  f32x4 acc[4][4];
#pragma unroll
  for (int i = 0; i < 4; ++i)
#pragma unroll
    for (int j = 0; j < 4; ++j) acc[i][j] = (f32x4){0.f, 0.f, 0.f, 0.f};

  for (int s0 = 0; s0 < smax; s0 += 64) {
    __syncthreads();
    if (USE_WF16) {
#pragma unroll
      for (int i = 0; i < 4; ++i) {
        const int cc = (wv << 8) + (i << 6) + lane;  // 16B chunk id 0..1023
        const int rowa = cc >> 3, q = cc & 7;
        const int gq = q ^ (rowa & 7);
        const int ldsoff = (((wv << 8) + (i << 6)) << 3);  // wave-uniform, shorts
        gl2lds16(wf + wbase + (size_t)(t0 + rowa) * T_ + s0 + (gq << 3), &Aw[ldsoff]);
      }
    } else {
      const int rowa = tid >> 1, half = tid & 1;
      const float* g = w + wbase + (size_t)(t0 + rowa) * T_ + s0 + (half << 5);
      const int rs = rowa & 7;
#pragma unroll
      for (int p = 0; p < 4; ++p) {
        const float4 va = ((const float4*)g)[2 * p];
        const float4 vb = ((const float4*)g)[2 * p + 1];
        u16x8 pk = {f2h(va.x), f2h(va.y), f2h(va.z), f2h(va.w),
                    f2h(vb.x), f2h(vb.y), f2h(vb.z), f2h(vb.w)};
        const int c = (half << 2) + p;
        *(u16x8*)&Aw[(rowa << 6) + ((c ^ rs) << 3)] = pk;
      }
    }
#pragma unroll
    for (int i = 0; i < 4; ++i) {
      const int cc = (wv << 8) + (i << 6) + lane;
      const int rowb = cc >> 3, q = cc & 7;
      const int gq = q ^ (rowb & 7);
      const int ldsoff = (((wv << 8) + (i << 6)) << 3);
      gl2lds16(xth + xtb + (size_t)(d0 + rowb) * T_ + s0 + (gq << 3), &Bx[ldsoff]);
    }
    __syncthreads();
#pragma unroll
    for (int h = 0; h < 2; ++h) {
      f16x8 a[4];
#pragma unroll
      for (int i = 0; i < 4; ++i) {
        const int ar = wr + (i << 4) + r16;
        a[i] = *(const f16x8*)&Aw[(ar << 6) + ((((h << 2) | quad) ^ (ar & 7)) << 3)];
      }
#pragma unroll
      for (int j = 0; j < 4; ++j) {
        const int br = wc + (j << 4) + r16;
        const f16x8 bbj = *(const f16x8*)&Bx[(br << 6) + ((((h << 2) | quad) ^ (br & 7)) << 3)];
#pragma unroll
        for (int i = 0; i < 4; ++i)
          acc[i][j] = __builtin_amdgcn_mfma_f32_16x16x32_f16(a[i], bbj, acc[i][j], 0, 0, 0);
      }
    }
  }

  float* ob = out + (size_t)b * T_ * D_;
#pragma unroll
  for (int i = 0; i < 4; ++i)
#pragma unroll
    for (int j = 0; j < 4; ++j) {
      const int rr = t0 + wr + (i << 4) + (quad << 2);
      const int cc = d0 + wc + (j << 4) + r16;
#pragma unroll
      for (int rg = 0; rg < 4; ++rg)
        ob[(size_t)(rr + rg) * D_ + cc] = acc[i][j][rg];
    }
}

// ---------------------------------------------------------------------------
// Row 0 of out = mean over all T rows of x. 512 blocks (was 64: single-block
// streaming made it a ~28 µs serial tail; now ~6 µs).
// ---------------------------------------------------------------------------
__global__ __launch_bounds__(256) void row0_partial(const float* __restrict__ x,
                                                    float* __restrict__ part) {
  const int tc = blockIdx.x, b = blockIdx.y;  // tc 0..63, 32 rows each
  const int tid = threadIdx.x;
  const float* xb = x + ((size_t)b * T_ + (tc << 5)) * D_;
  float4 s = {0.f, 0.f, 0.f, 0.f};
#pragma unroll 4
  for (int r = 0; r < 32; ++r) {
    const float4 v = *(const float4*)(xb + (size_t)r * D_ + (tid << 2));
    s.x += v.x; s.y += v.y; s.z += v.z; s.w += v.w;
  }
  *(float4*)(part + ((size_t)((b << 6) + tc)) * D_ + (tid << 2)) = s;
}

__global__ __launch_bounds__(256) void row0_reduce(const float* __restrict__ part,
                                                   float* __restrict__ out) {
  const int b = blockIdx.x;
  const int tid = threadIdx.x;
  float4 s = {0.f, 0.f, 0.f, 0.f};
#pragma unroll 8
  for (int p = 0; p < 64; ++p) {
    const float4 v = *(const float4*)(part + ((size_t)((b << 6) + p)) * D_ + (tid << 2));
    s.x += v.x; s.y += v.y; s.z += v.z; s.w += v.w;
  }
  const float sc = 1.0f / 2048.0f;
  float4 o = {s.x * sc, s.y * sc, s.z * sc, s.w * sc};
  *(float4*)(out + (size_t)b * T_ * D_ + (tid << 2)) = o;  // row t=0
}

// ---------------------------------------------------------------------------
extern "C" void kernel_launch(void* const* d_in, const int* in_sizes, int n_in,
                              void* d_out, int out_size, void* d_ws, size_t ws_size,
                              hipStream_t stream) {
  const float* x = (const float*)d_in[0];
  float* att_vec = (float*)d_out;                   // [B,T,D] output 0
  float* w = (float*)d_out + (size_t)B_ * T_ * D_;  // [B,T,T] output 1

  // xh/xl (bf16, row-major) staged in the att_vec region; consumed by scores
  // before av/row0 overwrite it.
  unsigned short* xh = (unsigned short*)att_vec;
  unsigned short* xl = xh + (size_t)B_ * T_ * D_;
  // workspace: xT fp16 (33.5 MB) + W fp16 (67 MB) + row0 partials (2 MB)
  const size_t xthN = (size_t)B_ * D_ * T_;
  const size_t wfN = (size_t)B_ * T_ * T_;
  unsigned short* xth = (unsigned short*)d_ws;
  unsigned short* wf16 = xth + xthN;
  const size_t need = xthN * 2 + wfN * 2 + (size_t)512 * D_ * 4;
  const bool use_wf16 = (ws_size >= need);
  float* part = use_wf16 ? (float*)(wf16 + wfN) : (float*)(xth + xthN);

  prep_kernel<<<dim3(D_ / 64, T_ / 64, B_), 256, 0, stream>>>(x, xh, xl, xth);
  scores_mfma<<<dim3(8 * 136), 256, 0, stream>>>(xh, xl, w);
  if (use_wf16) {
    softmax_kernel<true><<<dim3(B_ * T_ / 4), 256, 0, stream>>>(w, wf16);
    av_mfma<true><<<dim3(128, 1, B_), 256, 0, stream>>>(w, wf16, xth, att_vec);
  } else {
    softmax_kernel<false><<<dim3(B_ * T_ / 4), 256, 0, stream>>>(w, wf16);
    av_mfma<false><<<dim3(128, 1, B_), 256, 0, stream>>>(w, wf16, xth, att_vec);
  }
  row0_partial<<<dim3(64, B_), 256, 0, stream>>>(x, part);
  row0_reduce<<<dim3(B_), 256, 0, stream>>>(part, att_vec);
}

// Round 4
// 505.615 us; speedup vs baseline: 1.1503x; 1.0079x over previous
//
#include <hip/hip_runtime.h>

#define B_ 8
#define T_ 2048
#define D_ 1024

typedef __attribute__((ext_vector_type(8))) short bf16x8;
typedef __attribute__((ext_vector_type(8))) _Float16 f16x8;
typedef __attribute__((ext_vector_type(4))) float f32x4;
typedef __attribute__((ext_vector_type(8))) unsigned short u16x8;
typedef __attribute__((ext_vector_type(4))) unsigned short u16x4;

__device__ __forceinline__ unsigned short f2bf(float f) {
  union { float f; unsigned u; } v; v.f = f;
  unsigned r = v.u + 0x7FFFu + ((v.u >> 16) & 1u);  // RNE (finite inputs only)
  return (unsigned short)(r >> 16);
}
__device__ __forceinline__ float bf2f(unsigned short h) {
  union { unsigned u; float f; } v; v.u = ((unsigned)h) << 16; return v.f;
}
__device__ __forceinline__ unsigned short f2h(float f) {
  union { _Float16 h; unsigned short u; } v; v.h = (_Float16)f; return v.u;
}

// async global->LDS, 16B/lane; LDS dest = wave-uniform base + lane*16
__device__ __forceinline__ void gl2lds16(const void* g, void* l) {
  __builtin_amdgcn_global_load_lds(
      (__attribute__((address_space(1))) void*)g,
      (__attribute__((address_space(3))) void*)l, 16, 0, 0);
}

// ---------------------------------------------------------------------------
// Prep: x fp32 -> x_hi/x_lo bf16 (row-major, for scores) + xT fp16 [b,d,t].
// Rewritten for coalesced global access: the old mapping had lane = row, so
// every 8B store was a 64-lane scatter at 2-4KB stride (~4x sector
// amplification on 96MB + 64-way VMEM serialization). Now 4-lane groups are
// column-contiguous: reads = 64B/line full, xh/xl stores = 32B runs,
// xth stores = 64B runs. Transpose staged via padded LDS (stride 136B,
// <=2-way conflicts = free).
// ---------------------------------------------------------------------------
__global__ __launch_bounds__(256) void prep_kernel(
    const float* __restrict__ x,
    unsigned short* __restrict__ xh, unsigned short* __restrict__ xl,
    unsigned short* __restrict__ xth) {
  const int b = blockIdx.z;
  const int t0 = blockIdx.y << 6;
  const int d0 = blockIdx.x << 6;
  __shared__ unsigned short tf[64][68];  // [d][t], fp16 bits
  const int tid = threadIdx.x;
  // Phase 1: r = t-row (16 rows/wave), cq*4 + k*16 = column
  const int r = tid >> 2, cq = tid & 3;
  const size_t xoff = ((size_t)b * T_ + t0 + r) * D_ + d0;
#pragma unroll
  for (int k = 0; k < 4; ++k) {
    const int col = (cq << 2) + (k << 4);  // lanes 0..3 -> 64B contiguous
    const float4 v = *(const float4*)(x + xoff + col);
    const unsigned short h0 = f2bf(v.x), h1 = f2bf(v.y), h2 = f2bf(v.z), h3 = f2bf(v.w);
    const unsigned short l0 = f2bf(v.x - bf2f(h0)), l1 = f2bf(v.y - bf2f(h1));
    const unsigned short l2 = f2bf(v.z - bf2f(h2)), l3 = f2bf(v.w - bf2f(h3));
    u16x4 hv = {h0, h1, h2, h3}, lv = {l0, l1, l2, l3};
    *(u16x4*)(xh + xoff + col) = hv;  // 32B contiguous per 4-lane group
    *(u16x4*)(xl + xoff + col) = lv;
    tf[col + 0][r] = f2h(v.x); tf[col + 1][r] = f2h(v.y);
    tf[col + 2][r] = f2h(v.z); tf[col + 3][r] = f2h(v.w);
  }
  __syncthreads();
  // Phase 2: dr = d-row, lanes 0..3 cover 64B contiguous along t
  const int dr = tid >> 2, tq = tid & 3;
  const size_t toff = ((size_t)b * D_ + d0 + dr) * T_ + t0;
#pragma unroll
  for (int c = 0; c < 2; ++c) {
    const int tcol = (tq << 3) + (c << 5);
    *(u16x8*)(xth + toff + tcol) = *(const u16x8*)&tf[dr][tcol];
  }
}

// ---------------------------------------------------------------------------
// Scores: S = x.x^T, causal tiles, 3-product split-bf16 MFMA (err ~2^-17).
// 128x128 tile, BK=32, global_load_lds staging, XOR-swizzled LDS chunk slots.
// Flat 1088-block causal grid, bijective XCD swizzle (XCD k == batch k),
// __launch_bounds__(256,4), streamed B fragments. At the m97-structure
// MfmaUtil ceiling (~37%) — untouched.
// ---------------------------------------------------------------------------
__global__ __launch_bounds__(256, 4) void scores_mfma(
    const unsigned short* __restrict__ xh, const unsigned short* __restrict__ xl,
    float* __restrict__ w) {
  const int id = blockIdx.x;
  const int sid = ((id & 7) * 136) + (id >> 3);
  const int b = sid / 136;
  const int L = sid - b * 136;
  int tt = (int)((sqrtf(8.f * (float)L + 1.f) - 1.f) * 0.5f);
  while (((tt + 1) * (tt + 2) >> 1) <= L) ++tt;
  while (((tt * (tt + 1)) >> 1) > L) --tt;
  const int ts = L - ((tt * (tt + 1)) >> 1);

  const int t0 = tt << 7, s0 = ts << 7;
  __shared__ unsigned short Ah[128 * 32];
  __shared__ unsigned short Al[128 * 32];
  __shared__ unsigned short Bh[128 * 32];
  __shared__ unsigned short Bl[128 * 32];
  const int tid = threadIdx.x;
  const int lane = tid & 63, wv = tid >> 6;
  const int wr = (wv >> 1) << 6, wc = (wv & 1) << 6;
  const int quad = lane >> 4, r16 = lane & 15;
  const int swz = ((quad ^ (r16 & 3) ^ ((r16 >> 2) & 1)) << 3);  // shorts
  const size_t xb = (size_t)b * T_ * D_;

  f32x4 acc[4][4];
#pragma unroll
  for (int i = 0; i < 4; ++i)
#pragma unroll
    for (int j = 0; j < 4; ++j) acc[i][j] = (f32x4){0.f, 0.f, 0.f, 0.f};

  for (int k0 = 0; k0 < D_; k0 += 32) {
    __syncthreads();
#pragma unroll
    for (int i = 0; i < 2; ++i) {
      const int cc = (wv << 7) + (i << 6) + lane;  // 16B chunk id 0..511
      const int row = cc >> 2, q = cc & 3;
      const int gq = q ^ (row & 3) ^ ((row >> 2) & 1);
      const int ldsoff = (((wv << 7) + (i << 6)) << 3);  // wave-uniform, shorts
      const size_t ga = xb + (size_t)(t0 + row) * D_ + k0 + (gq << 3);
      const size_t gb = xb + (size_t)(s0 + row) * D_ + k0 + (gq << 3);
      gl2lds16(xh + ga, &Ah[ldsoff]);
      gl2lds16(xl + ga, &Al[ldsoff]);
      gl2lds16(xh + gb, &Bh[ldsoff]);
      gl2lds16(xl + gb, &Bl[ldsoff]);
    }
    __syncthreads();
    bf16x8 ah[4], al[4];
#pragma unroll
    for (int i = 0; i < 4; ++i) {
      const int ra = ((wr + (i << 4) + r16) << 5) + swz;
      ah[i] = *(const bf16x8*)&Ah[ra];
      al[i] = *(const bf16x8*)&Al[ra];
    }
#pragma unroll
    for (int j = 0; j < 4; ++j) {
      const int rb = ((wc + (j << 4) + r16) << 5) + swz;
      const bf16x8 bhj = *(const bf16x8*)&Bh[rb];
      const bf16x8 blj = *(const bf16x8*)&Bl[rb];
#pragma unroll
      for (int i = 0; i < 4; ++i)
        acc[i][j] = __builtin_amdgcn_mfma_f32_16x16x32_bf16(ah[i], bhj, acc[i][j], 0, 0, 0);
#pragma unroll
      for (int i = 0; i < 4; ++i)
        acc[i][j] = __builtin_amdgcn_mfma_f32_16x16x32_bf16(ah[i], blj, acc[i][j], 0, 0, 0);
#pragma unroll
      for (int i = 0; i < 4; ++i)
        acc[i][j] = __builtin_amdgcn_mfma_f32_16x16x32_bf16(al[i], bhj, acc[i][j], 0, 0, 0);
    }
  }

  float* wb = w + (size_t)b * T_ * T_;
#pragma unroll
  for (int i = 0; i < 4; ++i)
#pragma unroll
    for (int j = 0; j < 4; ++j) {
      const int rr = t0 + wr + (i << 4) + (quad << 2);
      const int cc = s0 + wc + (j << 4) + r16;
#pragma unroll
      for (int rg = 0; rg < 4; ++rg)
        wb[(size_t)(rr + rg) * T_ + cc] = acc[i][j][rg];
    }
}

// ---------------------------------------------------------------------------
// Softmax: one wave per row, float4-vectorized. Masked chunk loads skip the
// upper half; per-element select keeps garbage out of the max. Writes full
// fp32 rows and, if EMIT, fp16 W up to the 128-tile boundary.
// ---------------------------------------------------------------------------
template <bool EMIT>
__global__ __launch_bounds__(256) void softmax_kernel(float* __restrict__ w,
                                                      unsigned short* __restrict__ wf) {
  const int row = (blockIdx.x << 2) + (threadIdx.x >> 6);  // b*T + t
  const int t = row & (T_ - 1);
  const int lane = threadIdx.x & 63;
  float* wr = w + (size_t)row * T_;
  unsigned short* wfr = wf + (size_t)row * T_;

  if (t == 0) {
    const float u = 1.0f / 2048.0f;
    const float4 uv = {u, u, u, u};
#pragma unroll
    for (int k = 0; k < 8; ++k) *(float4*)&wr[(lane << 2) + (k << 8)] = uv;
    if (EMIT && lane < 32) {  // av reads row 0 only s<128
      u16x4 z = {0, 0, 0, 0};
      *(u16x4*)&wfr[lane << 2] = z;
    }
    return;
  }

  float4 v[8];
  float m = -3.0e38f;
#pragma unroll
  for (int k = 0; k < 8; ++k) {
    const int s = (lane << 2) + (k << 8);
    float4 val = {-1.0e30f, -1.0e30f, -1.0e30f, -1.0e30f};
    if (s < t) {  // exec-masked: fully-upper chunks never fetched
      const float4 g = *(const float4*)&wr[s];
      val.x = g.x;
      val.y = (s + 1 < t) ? g.y : -1.0e30f;
      val.z = (s + 2 < t) ? g.z : -1.0e30f;
      val.w = (s + 3 < t) ? g.w : -1.0e30f;
    }
    v[k] = val;
    m = fmaxf(m, fmaxf(fmaxf(val.x, val.y), fmaxf(val.z, val.w)));
  }
#pragma unroll
  for (int off = 32; off; off >>= 1) m = fmaxf(m, __shfl_xor(m, off));

  float l = 0.f;
#pragma unroll
  for (int k = 0; k < 8; ++k) {
    v[k].x = __expf(v[k].x - m);  // masked slots -> exactly 0.0f
    v[k].y = __expf(v[k].y - m);
    v[k].z = __expf(v[k].z - m);
    v[k].w = __expf(v[k].w - m);
    l += (v[k].x + v[k].y) + (v[k].z + v[k].w);
  }
#pragma unroll
  for (int off = 32; off; off >>= 1) l += __shfl_xor(l, off);
  const float inv = 1.0f / l;

  const int smax_emit = ((t >> 7) + 1) << 7;  // 128-tile boundary
#pragma unroll
  for (int k = 0; k < 8; ++k) {
    const int s = (lane << 2) + (k << 8);
    const float4 o = {v[k].x * inv, v[k].y * inv, v[k].z * inv, v[k].w * inv};
    *(float4*)&wr[s] = o;
    if (EMIT && s < smax_emit) {
      u16x4 h = {f2h(o.x), f2h(o.y), f2h(o.z), f2h(o.w)};
      *(u16x4*)&wfr[s] = h;
    }
  }
}

// ---------------------------------------------------------------------------
// AV: out = W.x, single-product fp16 MFMA. 128x128 tile, BK=64 (32KB LDS
// total -> 5 blocks/CU; 32 MFMAs/stage phase). 8-slot XOR swizzle.
// ---------------------------------------------------------------------------
template <bool USE_WF16>
__global__ __launch_bounds__(256, 4) void av_mfma(
    const float* __restrict__ w, const unsigned short* __restrict__ wf,
    const unsigned short* __restrict__ xth, float* __restrict__ out) {
  const int xid = blockIdx.x;
  const int td = xid >> 4;
  const int ti = xid & 15;
  const int tt = (ti < 8) ? ti : (23 - ti);  // XCD k gets {k, 15-k}
  const int b = blockIdx.z;
  const int t0 = tt << 7, d0 = td << 7;
  __shared__ unsigned short Aw[128 * 64];
  __shared__ unsigned short Bx[128 * 64];
  const int tid = threadIdx.x;
  const int lane = tid & 63, wv = tid >> 6;
  const int wr = (wv >> 1) << 6, wc = (wv & 1) << 6;
  const int quad = lane >> 4, r16 = lane & 15;
  const size_t xtb = (size_t)b * D_ * T_;
  const size_t wbase = (size_t)b * T_ * T_;
  const int smax = t0 + 128;

  f32x4 acc[4][4];
#pragma unroll
  for (int i = 0; i < 4; ++i)
#pragma unroll
    for (int j = 0; j < 4; ++j) acc[i][j] = (f32x4){0.f, 0.f, 0.f, 0.f};

  for (int s0 = 0; s0 < smax; s0 += 64) {
    __syncthreads();
    if (USE_WF16) {
#pragma unroll
      for (int i = 0; i < 4; ++i) {
        const int cc = (wv << 8) + (i << 6) + lane;  // 16B chunk id 0..1023
        const int rowa = cc >> 3, q = cc & 7;
        const int gq = q ^ (rowa & 7);
        const int ldsoff = (((wv << 8) + (i << 6)) << 3);  // wave-uniform, shorts
        gl2lds16(wf + wbase + (size_t)(t0 + rowa) * T_ + s0 + (gq << 3), &Aw[ldsoff]);
      }
    } else {
      const int rowa = tid >> 1, half = tid & 1;
      const float* g = w + wbase + (size_t)(t0 + rowa) * T_ + s0 + (half << 5);
      const int rs = rowa & 7;
#pragma unroll
      for (int p = 0; p < 4; ++p) {
        const float4 va = ((const float4*)g)[2 * p];
        const float4 vb = ((const float4*)g)[2 * p + 1];
        u16x8 pk = {f2h(va.x), f2h(va.y), f2h(va.z), f2h(va.w),
                    f2h(vb.x), f2h(vb.y), f2h(vb.z), f2h(vb.w)};
        const int c = (half << 2) + p;
        *(u16x8*)&Aw[(rowa << 6) + ((c ^ rs) << 3)] = pk;
      }
    }
#pragma unroll
    for (int i = 0; i < 4; ++i) {
      const int cc = (wv << 8) + (i << 6) + lane;
      const int rowb = cc >> 3, q = cc & 7;
      const int gq = q ^ (rowb & 7);
      const int ldsoff = (((wv << 8) + (i << 6)) << 3);
      gl2lds16(xth + xtb + (size_t)(d0 + rowb) * T_ + s0 + (gq << 3), &Bx[ldsoff]);
    }
    __syncthreads();
#pragma unroll
    for (int h = 0; h < 2; ++h) {
      f16x8 a[4];
#pragma unroll
      for (int i = 0; i < 4; ++i) {
        const int ar = wr + (i << 4) + r16;
        a[i] = *(const f16x8*)&Aw[(ar << 6) + ((((h << 2) | quad) ^ (ar & 7)) << 3)];
      }
#pragma unroll
      for (int j = 0; j < 4; ++j) {
        const int br = wc + (j << 4) + r16;
        const f16x8 bbj = *(const f16x8*)&Bx[(br << 6) + ((((h << 2) | quad) ^ (br & 7)) << 3)];
#pragma unroll
        for (int i = 0; i < 4; ++i)
          acc[i][j] = __builtin_amdgcn_mfma_f32_16x16x32_f16(a[i], bbj, acc[i][j], 0, 0, 0);
      }
    }
  }

  float* ob = out + (size_t)b * T_ * D_;
#pragma unroll
  for (int i = 0; i < 4; ++i)
#pragma unroll
    for (int j = 0; j < 4; ++j) {
      const int rr = t0 + wr + (i << 4) + (quad << 2);
      const int cc = d0 + wc + (j << 4) + r16;
#pragma unroll
      for (int rg = 0; rg < 4; ++rg)
        ob[(size_t)(rr + rg) * D_ + cc] = acc[i][j][rg];
    }
}

// ---------------------------------------------------------------------------
// Row 0 of out = mean over all T rows of x. 512 blocks.
// ---------------------------------------------------------------------------
__global__ __launch_bounds__(256) void row0_partial(const float* __restrict__ x,
                                                    float* __restrict__ part) {
  const int tc = blockIdx.x, b = blockIdx.y;  // tc 0..63, 32 rows each
  const int tid = threadIdx.x;
  const float* xb = x + ((size_t)b * T_ + (tc << 5)) * D_;
  float4 s = {0.f, 0.f, 0.f, 0.f};
#pragma unroll 4
  for (int r = 0; r < 32; ++r) {
    const float4 v = *(const float4*)(xb + (size_t)r * D_ + (tid << 2));
    s.x += v.x; s.y += v.y; s.z += v.z; s.w += v.w;
  }
  *(float4*)(part + ((size_t)((b << 6) + tc)) * D_ + (tid << 2)) = s;
}

__global__ __launch_bounds__(256) void row0_reduce(const float* __restrict__ part,
                                                   float* __restrict__ out) {
  const int b = blockIdx.x;
  const int tid = threadIdx.x;
  float4 s = {0.f, 0.f, 0.f, 0.f};
#pragma unroll 8
  for (int p = 0; p < 64; ++p) {
    const float4 v = *(const float4*)(part + ((size_t)((b << 6) + p)) * D_ + (tid << 2));
    s.x += v.x; s.y += v.y; s.z += v.z; s.w += v.w;
  }
  const float sc = 1.0f / 2048.0f;
  float4 o = {s.x * sc, s.y * sc, s.z * sc, s.w * sc};
  *(float4*)(out + (size_t)b * T_ * D_ + (tid << 2)) = o;  // row t=0
}

// ---------------------------------------------------------------------------
extern "C" void kernel_launch(void* const* d_in, const int* in_sizes, int n_in,
                              void* d_out, int out_size, void* d_ws, size_t ws_size,
                              hipStream_t stream) {
  const float* x = (const float*)d_in[0];
  float* att_vec = (float*)d_out;                   // [B,T,D] output 0
  float* w = (float*)d_out + (size_t)B_ * T_ * D_;  // [B,T,T] output 1

  // xh/xl (bf16, row-major) staged in the att_vec region; consumed by scores
  // before av/row0 overwrite it.
  unsigned short* xh = (unsigned short*)att_vec;
  unsigned short* xl = xh + (size_t)B_ * T_ * D_;
  // workspace: xT fp16 (33.5 MB) + W fp16 (67 MB) + row0 partials (2 MB)
  const size_t xthN = (size_t)B_ * D_ * T_;
  const size_t wfN = (size_t)B_ * T_ * T_;
  unsigned short* xth = (unsigned short*)d_ws;
  unsigned short* wf16 = xth + xthN;
  const size_t need = xthN * 2 + wfN * 2 + (size_t)512 * D_ * 4;
  const bool use_wf16 = (ws_size >= need);
  float* part = use_wf16 ? (float*)(wf16 + wfN) : (float*)(xth + xthN);

  prep_kernel<<<dim3(D_ / 64, T_ / 64, B_), 256, 0, stream>>>(x, xh, xl, xth);
  scores_mfma<<<dim3(8 * 136), 256, 0, stream>>>(xh, xl, w);
  if (use_wf16) {
    softmax_kernel<true><<<dim3(B_ * T_ / 4), 256, 0, stream>>>(w, wf16);
    av_mfma<true><<<dim3(128, 1, B_), 256, 0, stream>>>(w, wf16, xth, att_vec);
  } else {
    softmax_kernel<false><<<dim3(B_ * T_ / 4), 256, 0, stream>>>(w, wf16);
    av_mfma<false><<<dim3(128, 1, B_), 256, 0, stream>>>(w, wf16, xth, att_vec);
  }
  row0_partial<<<dim3(64, B_), 256, 0, stream>>>(x, part);
  row0_reduce<<<dim3(B_), 256, 0, stream>>>(part, att_vec);
}

// Round 6
// 468.571 us; speedup vs baseline: 1.2412x; 1.0791x over previous
//
#include <hip/hip_runtime.h>

#define B_ 8
#define T_ 2048
#define D_ 1024

typedef __attribute__((ext_vector_type(8))) short bf16x8;
typedef __attribute__((ext_vector_type(8))) _Float16 f16x8;
typedef __attribute__((ext_vector_type(4))) float f32x4;
typedef __attribute__((ext_vector_type(8))) unsigned short u16x8;
typedef __attribute__((ext_vector_type(4))) unsigned short u16x4;

__device__ __forceinline__ unsigned short f2bf(float f) {
  union { float f; unsigned u; } v; v.f = f;
  unsigned r = v.u + 0x7FFFu + ((v.u >> 16) & 1u);  // RNE (finite inputs only)
  return (unsigned short)(r >> 16);
}
__device__ __forceinline__ float bf2f(unsigned short h) {
  union { unsigned u; float f; } v; v.u = ((unsigned)h) << 16; return v.f;
}
__device__ __forceinline__ unsigned short f2h(float f) {
  union { _Float16 h; unsigned short u; } v; v.h = (_Float16)f; return v.u;
}
__device__ __forceinline__ float h2f(unsigned short u) {
  union { unsigned short u; _Float16 h; } v; v.u = u; return (float)v.h;
}

// async global->LDS, 16B/lane; LDS dest = wave-uniform base + lane*16
__device__ __forceinline__ void gl2lds16(const void* g, void* l) {
  __builtin_amdgcn_global_load_lds(
      (__attribute__((address_space(1))) void*)g,
      (__attribute__((address_space(3))) void*)l, 16, 0, 0);
}

// ---------------------------------------------------------------------------
// Prep: x fp32 -> x_hi/x_lo bf16 (row-major, for scores) + xT fp16 [b,d,t]
// + fused row0 column partial sums (one partial per (b, t-tile, d)), using
// the fp16 tile already staged in LDS (err ~1e-3 on the mean, tol 0.03).
// Coalesced: 4-lane groups are column-contiguous (64B reads, 32B xh/xl runs,
// 64B xth runs).
// ---------------------------------------------------------------------------
__global__ __launch_bounds__(256) void prep_kernel(
    const float* __restrict__ x,
    unsigned short* __restrict__ xh, unsigned short* __restrict__ xl,
    unsigned short* __restrict__ xth, float* __restrict__ part) {
  const int b = blockIdx.z;
  const int t0 = blockIdx.y << 6;
  const int d0 = blockIdx.x << 6;
  __shared__ unsigned short tf[64][68];  // [d][t], fp16 bits
  const int tid = threadIdx.x;
  // Phase 1: r = t-row (16 rows/wave), cq*4 + k*16 = column
  const int r = tid >> 2, cq = tid & 3;
  const size_t xoff = ((size_t)b * T_ + t0 + r) * D_ + d0;
#pragma unroll
  for (int k = 0; k < 4; ++k) {
    const int col = (cq << 2) + (k << 4);  // lanes 0..3 -> 64B contiguous
    const float4 v = *(const float4*)(x + xoff + col);
    const unsigned short h0 = f2bf(v.x), h1 = f2bf(v.y), h2 = f2bf(v.z), h3 = f2bf(v.w);
    const unsigned short l0 = f2bf(v.x - bf2f(h0)), l1 = f2bf(v.y - bf2f(h1));
    const unsigned short l2 = f2bf(v.z - bf2f(h2)), l3 = f2bf(v.w - bf2f(h3));
    u16x4 hv = {h0, h1, h2, h3}, lv = {l0, l1, l2, l3};
    *(u16x4*)(xh + xoff + col) = hv;  // 32B contiguous per 4-lane group
    *(u16x4*)(xl + xoff + col) = lv;
    tf[col + 0][r] = f2h(v.x); tf[col + 1][r] = f2h(v.y);
    tf[col + 2][r] = f2h(v.z); tf[col + 3][r] = f2h(v.w);
  }
  __syncthreads();
  // Phase 2: dr = d-row, lanes 0..3 cover 64B contiguous along t.
  // Each thread also accumulates sum over its 16 t's of x[t][d0+dr];
  // shfl over tq (lane bits 0..1) completes the 64-row column sum.
  const int dr = tid >> 2, tq = tid & 3;
  const size_t toff = ((size_t)b * D_ + d0 + dr) * T_ + t0;
  float cs = 0.f;
#pragma unroll
  for (int c = 0; c < 2; ++c) {
    const int tcol = (tq << 3) + (c << 5);
    const u16x8 vv = *(const u16x8*)&tf[dr][tcol];
    *(u16x8*)(xth + toff + tcol) = vv;
#pragma unroll
    for (int e = 0; e < 8; ++e) cs += h2f(vv[e]);
  }
  cs += __shfl_xor(cs, 1);
  cs += __shfl_xor(cs, 2);
  if (tq == 0)
    part[(((size_t)b << 5) + blockIdx.y) * D_ + d0 + dr] = cs;
}

// ---------------------------------------------------------------------------
// Scores: S = x.x^T, causal tiles, 3-product split-bf16 MFMA (err ~2^-17).
// 128x128 tile, BK=32, global_load_lds staging, XOR-swizzled LDS chunk slots.
// Flat 1088-block causal grid, bijective XCD swizzle (XCD k == batch k),
// __launch_bounds__(256,4), streamed B fragments. At the m97-structure
// MfmaUtil ceiling (~37%) — untouched (control).
// ---------------------------------------------------------------------------
__global__ __launch_bounds__(256, 4) void scores_mfma(
    const unsigned short* __restrict__ xh, const unsigned short* __restrict__ xl,
    float* __restrict__ w) {
  const int id = blockIdx.x;
  const int sid = ((id & 7) * 136) + (id >> 3);
  const int b = sid / 136;
  const int L = sid - b * 136;
  int tt = (int)((sqrtf(8.f * (float)L + 1.f) - 1.f) * 0.5f);
  while (((tt + 1) * (tt + 2) >> 1) <= L) ++tt;
  while (((tt * (tt + 1)) >> 1) > L) --tt;
  const int ts = L - ((tt * (tt + 1)) >> 1);

  const int t0 = tt << 7, s0 = ts << 7;
  __shared__ unsigned short Ah[128 * 32];
  __shared__ unsigned short Al[128 * 32];
  __shared__ unsigned short Bh[128 * 32];
  __shared__ unsigned short Bl[128 * 32];
  const int tid = threadIdx.x;
  const int lane = tid & 63, wv = tid >> 6;
  const int wr = (wv >> 1) << 6, wc = (wv & 1) << 6;
  const int quad = lane >> 4, r16 = lane & 15;
  const int swz = ((quad ^ (r16 & 3) ^ ((r16 >> 2) & 1)) << 3);  // shorts
  const size_t xb = (size_t)b * T_ * D_;

  f32x4 acc[4][4];
#pragma unroll
  for (int i = 0; i < 4; ++i)
#pragma unroll
    for (int j = 0; j < 4; ++j) acc[i][j] = (f32x4){0.f, 0.f, 0.f, 0.f};

  for (int k0 = 0; k0 < D_; k0 += 32) {
    __syncthreads();
#pragma unroll
    for (int i = 0; i < 2; ++i) {
      const int cc = (wv << 7) + (i << 6) + lane;  // 16B chunk id 0..511
      const int row = cc >> 2, q = cc & 3;
      const int gq = q ^ (row & 3) ^ ((row >> 2) & 1);
      const int ldsoff = (((wv << 7) + (i << 6)) << 3);  // wave-uniform, shorts
      const size_t ga = xb + (size_t)(t0 + row) * D_ + k0 + (gq << 3);
      const size_t gb = xb + (size_t)(s0 + row) * D_ + k0 + (gq << 3);
      gl2lds16(xh + ga, &Ah[ldsoff]);
      gl2lds16(xl + ga, &Al[ldsoff]);
      gl2lds16(xh + gb, &Bh[ldsoff]);
      gl2lds16(xl + gb, &Bl[ldsoff]);
    }
    __syncthreads();
    bf16x8 ah[4], al[4];
#pragma unroll
    for (int i = 0; i < 4; ++i) {
      const int ra = ((wr + (i << 4) + r16) << 5) + swz;
      ah[i] = *(const bf16x8*)&Ah[ra];
      al[i] = *(const bf16x8*)&Al[ra];
    }
#pragma unroll
    for (int j = 0; j < 4; ++j) {
      const int rb = ((wc + (j << 4) + r16) << 5) + swz;
      const bf16x8 bhj = *(const bf16x8*)&Bh[rb];
      const bf16x8 blj = *(const bf16x8*)&Bl[rb];
#pragma unroll
      for (int i = 0; i < 4; ++i)
        acc[i][j] = __builtin_amdgcn_mfma_f32_16x16x32_bf16(ah[i], bhj, acc[i][j], 0, 0, 0);
#pragma unroll
      for (int i = 0; i < 4; ++i)
        acc[i][j] = __builtin_amdgcn_mfma_f32_16x16x32_bf16(ah[i], blj, acc[i][j], 0, 0, 0);
#pragma unroll
      for (int i = 0; i < 4; ++i)
        acc[i][j] = __builtin_amdgcn_mfma_f32_16x16x32_bf16(al[i], bhj, acc[i][j], 0, 0, 0);
    }
  }

  float* wb = w + (size_t)b * T_ * T_;
#pragma unroll
  for (int i = 0; i < 4; ++i)
#pragma unroll
    for (int j = 0; j < 4; ++j) {
      const int rr = t0 + wr + (i << 4) + (quad << 2);
      const int cc = s0 + wc + (j << 4) + r16;
#pragma unroll
      for (int rg = 0; rg < 4; ++rg)
        wb[(size_t)(rr + rg) * T_ + cc] = acc[i][j][rg];
    }
}

// ---------------------------------------------------------------------------
// Softmax: one wave per row, float4-vectorized. Masked chunk loads skip the
// upper half. fp32 W stores are nontemporal via ext-vector f32x4
// (__builtin_nontemporal_store rejects HIP_vector_type float4). fp16 W
// (read by av) stays cached.
// ---------------------------------------------------------------------------
template <bool EMIT>
__global__ __launch_bounds__(256) void softmax_kernel(float* __restrict__ w,
                                                      unsigned short* __restrict__ wf) {
  const int row = (blockIdx.x << 2) + (threadIdx.x >> 6);  // b*T + t
  const int t = row & (T_ - 1);
  const int lane = threadIdx.x & 63;
  float* wr = w + (size_t)row * T_;
  unsigned short* wfr = wf + (size_t)row * T_;

  if (t == 0) {
    const float u = 1.0f / 2048.0f;
    const f32x4 uv = {u, u, u, u};
#pragma unroll
    for (int k = 0; k < 8; ++k)
      __builtin_nontemporal_store(uv, (f32x4*)&wr[(lane << 2) + (k << 8)]);
    if (EMIT && lane < 32) {  // av reads row 0 only s<128
      u16x4 z = {0, 0, 0, 0};
      *(u16x4*)&wfr[lane << 2] = z;
    }
    return;
  }

  float4 v[8];
  float m = -3.0e38f;
#pragma unroll
  for (int k = 0; k < 8; ++k) {
    const int s = (lane << 2) + (k << 8);
    float4 val = {-1.0e30f, -1.0e30f, -1.0e30f, -1.0e30f};
    if (s < t) {  // exec-masked: fully-upper chunks never fetched
      const float4 g = *(const float4*)&wr[s];
      val.x = g.x;
      val.y = (s + 1 < t) ? g.y : -1.0e30f;
      val.z = (s + 2 < t) ? g.z : -1.0e30f;
      val.w = (s + 3 < t) ? g.w : -1.0e30f;
    }
    v[k] = val;
    m = fmaxf(m, fmaxf(fmaxf(val.x, val.y), fmaxf(val.z, val.w)));
  }
#pragma unroll
  for (int off = 32; off; off >>= 1) m = fmaxf(m, __shfl_xor(m, off));

  float l = 0.f;
#pragma unroll
  for (int k = 0; k < 8; ++k) {
    v[k].x = __expf(v[k].x - m);  // masked slots -> exactly 0.0f
    v[k].y = __expf(v[k].y - m);
    v[k].z = __expf(v[k].z - m);
    v[k].w = __expf(v[k].w - m);
    l += (v[k].x + v[k].y) + (v[k].z + v[k].w);
  }
#pragma unroll
  for (int off = 32; off; off >>= 1) l += __shfl_xor(l, off);
  const float inv = 1.0f / l;

  const int smax_emit = ((t >> 7) + 1) << 7;  // 128-tile boundary
#pragma unroll
  for (int k = 0; k < 8; ++k) {
    const int s = (lane << 2) + (k << 8);
    const f32x4 o = {v[k].x * inv, v[k].y * inv, v[k].z * inv, v[k].w * inv};
    __builtin_nontemporal_store(o, (f32x4*)&wr[s]);
    if (EMIT && s < smax_emit) {
      u16x4 h = {f2h(o[0]), f2h(o[1]), f2h(o[2]), f2h(o[3])};
      *(u16x4*)&wfr[s] = h;
    }
  }
}

// ---------------------------------------------------------------------------
// AV: out = W.x, single-product fp16 MFMA, 128x128 tile, BK=64, 8-slot XOR
// swizzle. UNIFORM-WORK blocks: each block owns the tt-pair {kp, 15-kp} and
// processes both tiles sequentially (34 s-steps every block) — immune to
// dispatch-order-dependent per-CU imbalance (the old 16x work spread put
// all-heavy blocks on the same CU: ~1.9x makespan). XCD = kp, so each XCD
// touches only 2 W strips. 512 blocks, 2/CU resident.
// ---------------------------------------------------------------------------
template <bool USE_WF16>
__global__ __launch_bounds__(256, 4) void av_mfma(
    const float* __restrict__ w, const unsigned short* __restrict__ wf,
    const unsigned short* __restrict__ xth, float* __restrict__ out) {
  const int xid = blockIdx.x;       // 0..63
  const int td = xid >> 3;          // 0..7
  const int kp = xid & 7;           // pair id; XCD = linear%8 = kp
  const int b = blockIdx.z;
  const int d0 = td << 7;
  __shared__ unsigned short Aw[128 * 64];
  __shared__ unsigned short Bx[128 * 64];
  const int tid = threadIdx.x;
  const int lane = tid & 63, wv = tid >> 6;
  const int wr = (wv >> 1) << 6, wc = (wv & 1) << 6;
  const int quad = lane >> 4, r16 = lane & 15;
  const size_t xtb = (size_t)b * D_ * T_;
  const size_t wbase = (size_t)b * T_ * T_;
  float* ob = out + (size_t)b * T_ * D_;

#pragma unroll 1
  for (int mtile = 0; mtile < 2; ++mtile) {
    const int tt = mtile ? (15 - kp) : kp;
    const int t0 = tt << 7;
    const int smax = t0 + 128;

    f32x4 acc[4][4];
#pragma unroll
    for (int i = 0; i < 4; ++i)
#pragma unroll
      for (int j = 0; j < 4; ++j) acc[i][j] = (f32x4){0.f, 0.f, 0.f, 0.f};

    for (int s0 = 0; s0 < smax; s0 += 64) {
      __syncthreads();
      if (USE_WF16) {
#pragma unroll
        for (int i = 0; i < 4; ++i) {
          const int cc = (wv << 8) + (i << 6) + lane;  // 16B chunk id 0..1023
          const int rowa = cc >> 3, q = cc & 7;
          const int gq = q ^ (rowa & 7);
          const int ldsoff = (((wv << 8) + (i << 6)) << 3);  // wave-uniform, shorts
          gl2lds16(wf + wbase + (size_t)(t0 + rowa) * T_ + s0 + (gq << 3), &Aw[ldsoff]);
        }
      } else {
        const int rowa = tid >> 1, half = tid & 1;
        const float* g = w + wbase + (size_t)(t0 + rowa) * T_ + s0 + (half << 5);
        const int rs = rowa & 7;
#pragma unroll
        for (int p = 0; p < 4; ++p) {
          const float4 va = ((const float4*)g)[2 * p];
          const float4 vb = ((const float4*)g)[2 * p + 1];
          u16x8 pk = {f2h(va.x), f2h(va.y), f2h(va.z), f2h(va.w),
                      f2h(vb.x), f2h(vb.y), f2h(vb.z), f2h(vb.w)};
          const int c = (half << 2) + p;
          *(u16x8*)&Aw[(rowa << 6) + ((c ^ rs) << 3)] = pk;
        }
      }
#pragma unroll
      for (int i = 0; i < 4; ++i) {
        const int cc = (wv << 8) + (i << 6) + lane;
        const int rowb = cc >> 3, q = cc & 7;
        const int gq = q ^ (rowb & 7);
        const int ldsoff = (((wv << 8) + (i << 6)) << 3);
        gl2lds16(xth + xtb + (size_t)(d0 + rowb) * T_ + s0 + (gq << 3), &Bx[ldsoff]);
      }
      __syncthreads();
#pragma unroll
      for (int h = 0; h < 2; ++h) {
        f16x8 a[4];
#pragma unroll
        for (int i = 0; i < 4; ++i) {
          const int ar = wr + (i << 4) + r16;
          a[i] = *(const f16x8*)&Aw[(ar << 6) + ((((h << 2) | quad) ^ (ar & 7)) << 3)];
        }
#pragma unroll
        for (int j = 0; j < 4; ++j) {
          const int br = wc + (j << 4) + r16;
          const f16x8 bbj = *(const f16x8*)&Bx[(br << 6) + ((((h << 2) | quad) ^ (br & 7)) << 3)];
#pragma unroll
          for (int i = 0; i < 4; ++i)
            acc[i][j] = __builtin_amdgcn_mfma_f32_16x16x32_f16(a[i], bbj, acc[i][j], 0, 0, 0);
        }
      }
    }

#pragma unroll
    for (int i = 0; i < 4; ++i)
#pragma unroll
      for (int j = 0; j < 4; ++j) {
        const int rr = t0 + wr + (i << 4) + (quad << 2);
        const int cc = d0 + wc + (j << 4) + r16;
#pragma unroll
        for (int rg = 0; rg < 4; ++rg)
          __builtin_nontemporal_store(acc[i][j][rg], &ob[(size_t)(rr + rg) * D_ + cc]);
      }
  }
}

// ---------------------------------------------------------------------------
// Row 0 of out = mean over all T rows of x: reduce the 32 per-t-tile
// partials produced by prep.
// ---------------------------------------------------------------------------
__global__ __launch_bounds__(256) void row0_reduce(const float* __restrict__ part,
                                                   float* __restrict__ out) {
  const int b = blockIdx.x;
  const int tid = threadIdx.x;
  float4 s = {0.f, 0.f, 0.f, 0.f};
#pragma unroll 8
  for (int p = 0; p < 32; ++p) {
    const float4 v = *(const float4*)(part + (((size_t)b << 5) + p) * D_ + (tid << 2));
    s.x += v.x; s.y += v.y; s.z += v.z; s.w += v.w;
  }
  const float sc = 1.0f / 2048.0f;
  float4 o = {s.x * sc, s.y * sc, s.z * sc, s.w * sc};
  *(float4*)(out + (size_t)b * T_ * D_ + (tid << 2)) = o;  // row t=0
}

// ---------------------------------------------------------------------------
extern "C" void kernel_launch(void* const* d_in, const int* in_sizes, int n_in,
                              void* d_out, int out_size, void* d_ws, size_t ws_size,
                              hipStream_t stream) {
  const float* x = (const float*)d_in[0];
  float* att_vec = (float*)d_out;                   // [B,T,D] output 0
  float* w = (float*)d_out + (size_t)B_ * T_ * D_;  // [B,T,T] output 1

  // xh/xl (bf16, row-major) staged in the att_vec region; consumed by scores
  // before av/row0 overwrite it.
  unsigned short* xh = (unsigned short*)att_vec;
  unsigned short* xl = xh + (size_t)B_ * T_ * D_;
  // workspace: xT fp16 (33.5 MB) + W fp16 (67 MB) + row0 partials (1 MB)
  const size_t xthN = (size_t)B_ * D_ * T_;
  const size_t wfN = (size_t)B_ * T_ * T_;
  unsigned short* xth = (unsigned short*)d_ws;
  unsigned short* wf16 = xth + xthN;
  const size_t need = xthN * 2 + wfN * 2 + (size_t)256 * D_ * 4;
  const bool use_wf16 = (ws_size >= need);
  float* part = use_wf16 ? (float*)(wf16 + wfN) : (float*)(xth + xthN);

  prep_kernel<<<dim3(D_ / 64, T_ / 64, B_), 256, 0, stream>>>(x, xh, xl, xth, part);
  scores_mfma<<<dim3(8 * 136), 256, 0, stream>>>(xh, xl, w);
  if (use_wf16) {
    softmax_kernel<true><<<dim3(B_ * T_ / 4), 256, 0, stream>>>(w, wf16);
    av_mfma<true><<<dim3(64, 1, B_), 256, 0, stream>>>(w, wf16, xth, att_vec);
  } else {
    softmax_kernel<false><<<dim3(B_ * T_ / 4), 256, 0, stream>>>(w, wf16);
    av_mfma<false><<<dim3(64, 1, B_), 256, 0, stream>>>(w, wf16, xth, att_vec);
  }
  row0_reduce<<<dim3(B_), 256, 0, stream>>>(part, att_vec);
}

// Round 7
// 464.155 us; speedup vs baseline: 1.2530x; 1.0095x over previous
//
#include <hip/hip_runtime.h>

#define B_ 8
#define T_ 2048
#define D_ 1024

typedef __attribute__((ext_vector_type(8))) short bf16x8;
typedef __attribute__((ext_vector_type(8))) _Float16 f16x8;
typedef __attribute__((ext_vector_type(4))) float f32x4;
typedef __attribute__((ext_vector_type(8))) unsigned short u16x8;
typedef __attribute__((ext_vector_type(4))) unsigned short u16x4;

__device__ __forceinline__ unsigned short f2bf(float f) {
  union { float f; unsigned u; } v; v.f = f;
  unsigned r = v.u + 0x7FFFu + ((v.u >> 16) & 1u);  // RNE (finite inputs only)
  return (unsigned short)(r >> 16);
}
__device__ __forceinline__ float bf2f(unsigned short h) {
  union { unsigned u; float f; } v; v.u = ((unsigned)h) << 16; return v.f;
}
__device__ __forceinline__ unsigned short f2h(float f) {
  union { _Float16 h; unsigned short u; } v; v.h = (_Float16)f; return v.u;
}
__device__ __forceinline__ float h2f(unsigned short u) {
  union { unsigned short u; _Float16 h; } v; v.u = u; return (float)v.h;
}

// async global->LDS, 16B/lane; LDS dest = wave-uniform base + lane*16
__device__ __forceinline__ void gl2lds16(const void* g, void* l) {
  __builtin_amdgcn_global_load_lds(
      (__attribute__((address_space(1))) void*)g,
      (__attribute__((address_space(3))) void*)l, 16, 0, 0);
}

// ---------------------------------------------------------------------------
// Prep: x fp32 -> x_hi/x_lo bf16 (row-major, for scores) + xT fp16 [b,d,t]
// + fused row0 column partial sums. Coalesced 4-lane column groups.
// ---------------------------------------------------------------------------
__global__ __launch_bounds__(256) void prep_kernel(
    const float* __restrict__ x,
    unsigned short* __restrict__ xh, unsigned short* __restrict__ xl,
    unsigned short* __restrict__ xth, float* __restrict__ part) {
  const int b = blockIdx.z;
  const int t0 = blockIdx.y << 6;
  const int d0 = blockIdx.x << 6;
  __shared__ unsigned short tf[64][68];  // [d][t], fp16 bits
  const int tid = threadIdx.x;
  const int r = tid >> 2, cq = tid & 3;
  const size_t xoff = ((size_t)b * T_ + t0 + r) * D_ + d0;
#pragma unroll
  for (int k = 0; k < 4; ++k) {
    const int col = (cq << 2) + (k << 4);  // lanes 0..3 -> 64B contiguous
    const float4 v = *(const float4*)(x + xoff + col);
    const unsigned short h0 = f2bf(v.x), h1 = f2bf(v.y), h2 = f2bf(v.z), h3 = f2bf(v.w);
    const unsigned short l0 = f2bf(v.x - bf2f(h0)), l1 = f2bf(v.y - bf2f(h1));
    const unsigned short l2 = f2bf(v.z - bf2f(h2)), l3 = f2bf(v.w - bf2f(h3));
    u16x4 hv = {h0, h1, h2, h3}, lv = {l0, l1, l2, l3};
    *(u16x4*)(xh + xoff + col) = hv;
    *(u16x4*)(xl + xoff + col) = lv;
    tf[col + 0][r] = f2h(v.x); tf[col + 1][r] = f2h(v.y);
    tf[col + 2][r] = f2h(v.z); tf[col + 3][r] = f2h(v.w);
  }
  __syncthreads();
  const int dr = tid >> 2, tq = tid & 3;
  const size_t toff = ((size_t)b * D_ + d0 + dr) * T_ + t0;
  float cs = 0.f;
#pragma unroll
  for (int c = 0; c < 2; ++c) {
    const int tcol = (tq << 3) + (c << 5);
    const u16x8 vv = *(const u16x8*)&tf[dr][tcol];
    *(u16x8*)(xth + toff + tcol) = vv;
#pragma unroll
    for (int e = 0; e < 8; ++e) cs += h2f(vv[e]);
  }
  cs += __shfl_xor(cs, 1);
  cs += __shfl_xor(cs, 2);
  if (tq == 0)
    part[(((size_t)b << 5) + blockIdx.y) * D_ + d0 + dr] = cs;
}

// ---------------------------------------------------------------------------
// Scores: S = x.x^T, causal tiles, 3-product split-bf16 MFMA (err ~2^-17).
// 128x128 tile, BK=32, XOR-swizzled LDS. THIS ROUND: T3+T4 pipeline —
// double-buffered LDS (64KB, 2 blocks/CU) + raw s_barrier + counted
// s_waitcnt vmcnt(8): the next K-step's 8 global_load_lds stay IN FLIGHT
// across the barrier instead of the compiler's full vmcnt(0) drain
// (L3-latency staging drain was ~60% of step time at 3x MFMA density).
// Race structure: barrierA (frees buf^1: all waves' prior ds_reads were
// MFMA-consumed) -> stage buf^1 -> vmcnt(8) (prev stage complete, new 8
// outstanding) -> barrierB (staging globally visible) -> compute buf.
// ---------------------------------------------------------------------------
__global__ __launch_bounds__(256, 2) void scores_mfma(
    const unsigned short* __restrict__ xh, const unsigned short* __restrict__ xl,
    float* __restrict__ w) {
  const int id = blockIdx.x;
  const int sid = ((id & 7) * 136) + (id >> 3);
  const int b = sid / 136;
  const int L = sid - b * 136;
  int tt = (int)((sqrtf(8.f * (float)L + 1.f) - 1.f) * 0.5f);
  while (((tt + 1) * (tt + 2) >> 1) <= L) ++tt;
  while (((tt * (tt + 1)) >> 1) > L) --tt;
  const int ts = L - ((tt * (tt + 1)) >> 1);

  const int t0 = tt << 7, s0 = ts << 7;
  __shared__ unsigned short Ah[2][128 * 32];
  __shared__ unsigned short Al[2][128 * 32];
  __shared__ unsigned short Bh[2][128 * 32];
  __shared__ unsigned short Bl[2][128 * 32];
  const int tid = threadIdx.x;
  const int lane = tid & 63, wv = tid >> 6;
  const int wr = (wv >> 1) << 6, wc = (wv & 1) << 6;
  const int quad = lane >> 4, r16 = lane & 15;
  const int swz = ((quad ^ (r16 & 3) ^ ((r16 >> 2) & 1)) << 3);  // shorts
  const size_t xb = (size_t)b * T_ * D_;

  // per-thread staging addresses (row/chunk decode hoisted out of the loop)
  const int cc0 = (wv << 7) + lane;          // i=0 chunk id
  const int cc1 = cc0 + 64;                  // i=1 chunk id
  const int row0 = cc0 >> 2, q0 = cc0 & 3;
  const int row1 = cc1 >> 2, q1 = cc1 & 3;
  const int gq0 = q0 ^ (row0 & 3) ^ ((row0 >> 2) & 1);
  const int gq1 = q1 ^ (row1 & 3) ^ ((row1 >> 2) & 1);
  const int lo0 = ((wv << 7) << 3);          // wave-uniform LDS offs (shorts)
  const int lo1 = (((wv << 7) + 64) << 3);

  f32x4 acc[4][4];
#pragma unroll
  for (int i = 0; i < 4; ++i)
#pragma unroll
    for (int j = 0; j < 4; ++j) acc[i][j] = (f32x4){0.f, 0.f, 0.f, 0.f};

#define SCORES_STAGE(nb, k0)                                                   \
  {                                                                            \
    const size_t ga0 = xb + (size_t)(t0 + row0) * D_ + (k0) + (gq0 << 3);      \
    const size_t gb0 = xb + (size_t)(s0 + row0) * D_ + (k0) + (gq0 << 3);      \
    const size_t ga1 = xb + (size_t)(t0 + row1) * D_ + (k0) + (gq1 << 3);      \
    const size_t gb1 = xb + (size_t)(s0 + row1) * D_ + (k0) + (gq1 << 3);      \
    gl2lds16(xh + ga0, &Ah[nb][lo0]);                                          \
    gl2lds16(xl + ga0, &Al[nb][lo0]);                                          \
    gl2lds16(xh + gb0, &Bh[nb][lo0]);                                          \
    gl2lds16(xl + gb0, &Bl[nb][lo0]);                                          \
    gl2lds16(xh + ga1, &Ah[nb][lo1]);                                          \
    gl2lds16(xl + ga1, &Al[nb][lo1]);                                          \
    gl2lds16(xh + gb1, &Bh[nb][lo1]);                                          \
    gl2lds16(xl + gb1, &Bl[nb][lo1]);                                          \
  }

  // prologue: stage K-step 0 into buffer 0
  SCORES_STAGE(0, 0)

  for (int step = 0; step < 32; ++step) {
    const int cur = step & 1;
    // barrier A: all waves' compute(step-1) done -> buf[cur^1] free to overwrite
    __builtin_amdgcn_s_barrier();
    if (step + 1 < 32) {
      SCORES_STAGE(cur ^ 1, (step + 1) << 5)
      asm volatile("s_waitcnt vmcnt(8)" ::: "memory");  // prev stage complete; 8 new in flight
    } else {
      asm volatile("s_waitcnt vmcnt(0)" ::: "memory");
    }
    __builtin_amdgcn_sched_barrier(0);
    // barrier B: buf[cur] staging globally visible
    __builtin_amdgcn_s_barrier();

    bf16x8 ah[4], al[4];
#pragma unroll
    for (int i = 0; i < 4; ++i) {
      const int ra = ((wr + (i << 4) + r16) << 5) + swz;
      ah[i] = *(const bf16x8*)&Ah[cur][ra];
      al[i] = *(const bf16x8*)&Al[cur][ra];
    }
#pragma unroll
    for (int j = 0; j < 4; ++j) {
      const int rb = ((wc + (j << 4) + r16) << 5) + swz;
      const bf16x8 bhj = *(const bf16x8*)&Bh[cur][rb];
      const bf16x8 blj = *(const bf16x8*)&Bl[cur][rb];
#pragma unroll
      for (int i = 0; i < 4; ++i)
        acc[i][j] = __builtin_amdgcn_mfma_f32_16x16x32_bf16(ah[i], bhj, acc[i][j], 0, 0, 0);
#pragma unroll
      for (int i = 0; i < 4; ++i)
        acc[i][j] = __builtin_amdgcn_mfma_f32_16x16x32_bf16(ah[i], blj, acc[i][j], 0, 0, 0);
#pragma unroll
      for (int i = 0; i < 4; ++i)
        acc[i][j] = __builtin_amdgcn_mfma_f32_16x16x32_bf16(al[i], bhj, acc[i][j], 0, 0, 0);
    }
  }
#undef SCORES_STAGE

  float* wb = w + (size_t)b * T_ * T_;
#pragma unroll
  for (int i = 0; i < 4; ++i)
#pragma unroll
    for (int j = 0; j < 4; ++j) {
      const int rr = t0 + wr + (i << 4) + (quad << 2);
      const int cc = s0 + wc + (j << 4) + r16;
#pragma unroll
      for (int rg = 0; rg < 4; ++rg)
        wb[(size_t)(rr + rg) * T_ + cc] = acc[i][j][rg];
    }
}

// ---------------------------------------------------------------------------
// Softmax: one wave per row, float4-vectorized, nt fp32 stores (f32x4).
// ---------------------------------------------------------------------------
template <bool EMIT>
__global__ __launch_bounds__(256) void softmax_kernel(float* __restrict__ w,
                                                      unsigned short* __restrict__ wf) {
  const int row = (blockIdx.x << 2) + (threadIdx.x >> 6);  // b*T + t
  const int t = row & (T_ - 1);
  const int lane = threadIdx.x & 63;
  float* wr = w + (size_t)row * T_;
  unsigned short* wfr = wf + (size_t)row * T_;

  if (t == 0) {
    const float u = 1.0f / 2048.0f;
    const f32x4 uv = {u, u, u, u};
#pragma unroll
    for (int k = 0; k < 8; ++k)
      __builtin_nontemporal_store(uv, (f32x4*)&wr[(lane << 2) + (k << 8)]);
    if (EMIT && lane < 32) {  // av reads row 0 only s<128
      u16x4 z = {0, 0, 0, 0};
      *(u16x4*)&wfr[lane << 2] = z;
    }
    return;
  }

  float4 v[8];
  float m = -3.0e38f;
#pragma unroll
  for (int k = 0; k < 8; ++k) {
    const int s = (lane << 2) + (k << 8);
    float4 val = {-1.0e30f, -1.0e30f, -1.0e30f, -1.0e30f};
    if (s < t) {  // exec-masked: fully-upper chunks never fetched
      const float4 g = *(const float4*)&wr[s];
      val.x = g.x;
      val.y = (s + 1 < t) ? g.y : -1.0e30f;
      val.z = (s + 2 < t) ? g.z : -1.0e30f;
      val.w = (s + 3 < t) ? g.w : -1.0e30f;
    }
    v[k] = val;
    m = fmaxf(m, fmaxf(fmaxf(val.x, val.y), fmaxf(val.z, val.w)));
  }
#pragma unroll
  for (int off = 32; off; off >>= 1) m = fmaxf(m, __shfl_xor(m, off));

  float l = 0.f;
#pragma unroll
  for (int k = 0; k < 8; ++k) {
    v[k].x = __expf(v[k].x - m);  // masked slots -> exactly 0.0f
    v[k].y = __expf(v[k].y - m);
    v[k].z = __expf(v[k].z - m);
    v[k].w = __expf(v[k].w - m);
    l += (v[k].x + v[k].y) + (v[k].z + v[k].w);
  }
#pragma unroll
  for (int off = 32; off; off >>= 1) l += __shfl_xor(l, off);
  const float inv = 1.0f / l;

  const int smax_emit = ((t >> 7) + 1) << 7;  // 128-tile boundary
#pragma unroll
  for (int k = 0; k < 8; ++k) {
    const int s = (lane << 2) + (k << 8);
    const f32x4 o = {v[k].x * inv, v[k].y * inv, v[k].z * inv, v[k].w * inv};
    __builtin_nontemporal_store(o, (f32x4*)&wr[s]);
    if (EMIT && s < smax_emit) {
      u16x4 h = {f2h(o[0]), f2h(o[1]), f2h(o[2]), f2h(o[3])};
      *(u16x4*)&wfr[s] = h;
    }
  }
}

// ---------------------------------------------------------------------------
// AV: out = W.x, single-product fp16 MFMA, 128x128 tile, BK=64, 8-slot XOR
// swizzle. Uniform-work paired blocks {kp, 15-kp}; nt out stores.
// ---------------------------------------------------------------------------
template <bool USE_WF16>
__global__ __launch_bounds__(256, 4) void av_mfma(
    const float* __restrict__ w, const unsigned short* __restrict__ wf,
    const unsigned short* __restrict__ xth, float* __restrict__ out) {
  const int xid = blockIdx.x;       // 0..63
  const int td = xid >> 3;          // 0..7
  const int kp = xid & 7;           // pair id; XCD = linear%8 = kp
  const int b = blockIdx.z;
  const int d0 = td << 7;
  __shared__ unsigned short Aw[128 * 64];
  __shared__ unsigned short Bx[128 * 64];
  const int tid = threadIdx.x;
  const int lane = tid & 63, wv = tid >> 6;
  const int wr = (wv >> 1) << 6, wc = (wv & 1) << 6;
  const int quad = lane >> 4, r16 = lane & 15;
  const size_t xtb = (size_t)b * D_ * T_;
  const size_t wbase = (size_t)b * T_ * T_;
  float* ob = out + (size_t)b * T_ * D_;

#pragma unroll 1
  for (int mtile = 0; mtile < 2; ++mtile) {
    const int tt = mtile ? (15 - kp) : kp;
    const int t0 = tt << 7;
    const int smax = t0 + 128;

    f32x4 acc[4][4];
#pragma unroll
    for (int i = 0; i < 4; ++i)
#pragma unroll
      for (int j = 0; j < 4; ++j) acc[i][j] = (f32x4){0.f, 0.f, 0.f, 0.f};

    for (int s0 = 0; s0 < smax; s0 += 64) {
      __syncthreads();
      if (USE_WF16) {
#pragma unroll
        for (int i = 0; i < 4; ++i) {
          const int cc = (wv << 8) + (i << 6) + lane;  // 16B chunk id 0..1023
          const int rowa = cc >> 3, q = cc & 7;
          const int gq = q ^ (rowa & 7);
          const int ldsoff = (((wv << 8) + (i << 6)) << 3);  // wave-uniform, shorts
          gl2lds16(wf + wbase + (size_t)(t0 + rowa) * T_ + s0 + (gq << 3), &Aw[ldsoff]);
        }
      } else {
        const int rowa = tid >> 1, half = tid & 1;
        const float* g = w + wbase + (size_t)(t0 + rowa) * T_ + s0 + (half << 5);
        const int rs = rowa & 7;
#pragma unroll
        for (int p = 0; p < 4; ++p) {
          const float4 va = ((const float4*)g)[2 * p];
          const float4 vb = ((const float4*)g)[2 * p + 1];
          u16x8 pk = {f2h(va.x), f2h(va.y), f2h(va.z), f2h(va.w),
                      f2h(vb.x), f2h(vb.y), f2h(vb.z), f2h(vb.w)};
          const int c = (half << 2) + p;
          *(u16x8*)&Aw[(rowa << 6) + ((c ^ rs) << 3)] = pk;
        }
      }
#pragma unroll
      for (int i = 0; i < 4; ++i) {
        const int cc = (wv << 8) + (i << 6) + lane;
        const int rowb = cc >> 3, q = cc & 7;
        const int gq = q ^ (rowb & 7);
        const int ldsoff = (((wv << 8) + (i << 6)) << 3);
        gl2lds16(xth + xtb + (size_t)(d0 + rowb) * T_ + s0 + (gq << 3), &Bx[ldsoff]);
      }
      __syncthreads();
#pragma unroll
      for (int h = 0; h < 2; ++h) {
        f16x8 a[4];
#pragma unroll
        for (int i = 0; i < 4; ++i) {
          const int ar = wr + (i << 4) + r16;
          a[i] = *(const f16x8*)&Aw[(ar << 6) + ((((h << 2) | quad) ^ (ar & 7)) << 3)];
        }
#pragma unroll
        for (int j = 0; j < 4; ++j) {
          const int br = wc + (j << 4) + r16;
          const f16x8 bbj = *(const f16x8*)&Bx[(br << 6) + ((((h << 2) | quad) ^ (br & 7)) << 3)];
#pragma unroll
          for (int i = 0; i < 4; ++i)
            acc[i][j] = __builtin_amdgcn_mfma_f32_16x16x32_f16(a[i], bbj, acc[i][j], 0, 0, 0);
        }
      }
    }

#pragma unroll
    for (int i = 0; i < 4; ++i)
#pragma unroll
      for (int j = 0; j < 4; ++j) {
        const int rr = t0 + wr + (i << 4) + (quad << 2);
        const int cc = d0 + wc + (j << 4) + r16;
#pragma unroll
        for (int rg = 0; rg < 4; ++rg)
          __builtin_nontemporal_store(acc[i][j][rg], &ob[(size_t)(rr + rg) * D_ + cc]);
      }
  }
}

// ---------------------------------------------------------------------------
// Row 0 of out = mean over all T rows of x: reduce prep's 32 partials.
// ---------------------------------------------------------------------------
__global__ __launch_bounds__(256) void row0_reduce(const float* __restrict__ part,
                                                   float* __restrict__ out) {
  const int b = blockIdx.x;
  const int tid = threadIdx.x;
  float4 s = {0.f, 0.f, 0.f, 0.f};
#pragma unroll 8
  for (int p = 0; p < 32; ++p) {
    const float4 v = *(const float4*)(part + (((size_t)b << 5) + p) * D_ + (tid << 2));
    s.x += v.x; s.y += v.y; s.z += v.z; s.w += v.w;
  }
  const float sc = 1.0f / 2048.0f;
  float4 o = {s.x * sc, s.y * sc, s.z * sc, s.w * sc};
  *(float4*)(out + (size_t)b * T_ * D_ + (tid << 2)) = o;  // row t=0
}

// ---------------------------------------------------------------------------
extern "C" void kernel_launch(void* const* d_in, const int* in_sizes, int n_in,
                              void* d_out, int out_size, void* d_ws, size_t ws_size,
                              hipStream_t stream) {
  const float* x = (const float*)d_in[0];
  float* att_vec = (float*)d_out;                   // [B,T,D] output 0
  float* w = (float*)d_out + (size_t)B_ * T_ * D_;  // [B,T,T] output 1

  // xh/xl (bf16, row-major) staged in the att_vec region; consumed by scores
  // before av/row0 overwrite it.
  unsigned short* xh = (unsigned short*)att_vec;
  unsigned short* xl = xh + (size_t)B_ * T_ * D_;
  // workspace: xT fp16 (33.5 MB) + W fp16 (67 MB) + row0 partials (1 MB)
  const size_t xthN = (size_t)B_ * D_ * T_;
  const size_t wfN = (size_t)B_ * T_ * T_;
  unsigned short* xth = (unsigned short*)d_ws;
  unsigned short* wf16 = xth + xthN;
  const size_t need = xthN * 2 + wfN * 2 + (size_t)256 * D_ * 4;
  const bool use_wf16 = (ws_size >= need);
  float* part = use_wf16 ? (float*)(wf16 + wfN) : (float*)(xth + xthN);

  prep_kernel<<<dim3(D_ / 64, T_ / 64, B_), 256, 0, stream>>>(x, xh, xl, xth, part);
  scores_mfma<<<dim3(8 * 136), 256, 0, stream>>>(xh, xl, w);
  if (use_wf16) {
    softmax_kernel<true><<<dim3(B_ * T_ / 4), 256, 0, stream>>>(w, wf16);
    av_mfma<true><<<dim3(64, 1, B_), 256, 0, stream>>>(w, wf16, xth, att_vec);
  } else {
    softmax_kernel<false><<<dim3(B_ * T_ / 4), 256, 0, stream>>>(w, wf16);
    av_mfma<false><<<dim3(64, 1, B_), 256, 0, stream>>>(w, wf16, xth, att_vec);
  }
  row0_reduce<<<dim3(B_), 256, 0, stream>>>(part, att_vec);
}